// Round 13
// baseline (390.080 us; speedup 1.0000x reference)
//
#include <hip/hip_runtime.h>
#include <stdint.h>
#include <type_traits>

typedef unsigned short u16;
typedef short bf16x8 __attribute__((ext_vector_type(8)));
typedef float f32x4 __attribute__((ext_vector_type(4)));

__device__ __forceinline__ float b2f(u16 u) {
  union { uint32_t i; float f; } z; z.i = ((uint32_t)u) << 16; return z.f;
}
__device__ __forceinline__ u16 f2b(float f) {
  union { float f; uint32_t i; } z; z.f = f;
  uint32_t u = z.i;
  return (u16)((u + 0x7fffu + ((u >> 16) & 1u)) >> 16);
}
__device__ __forceinline__ f32x4 mfma16(bf16x8 a, bf16x8 b, f32x4 c) {
  return __builtin_amdgcn_mfma_f32_16x16x32_bf16(a, b, c, 0, 0, 0);
}
__device__ __forceinline__ void gload_lds16(const void* gp, void* lp) {
  __builtin_amdgcn_global_load_lds((__attribute__((address_space(1))) void*)gp,
                                   (__attribute__((address_space(3))) void*)lp,
                                   16, 0, 0);
}

// ---------------- small param prep ----------------
// par layout (floats): 0 sc1 | 256 sh1 | 512 sc2 | 768 sh2 | 1024 b8 | 1280 lnw
//                      1536 lnb | 1792 gamma | 2048 t1[8] | 2056 t2[8]
__global__ void prep_k(const float* lnw, const float* lnb, const float* gam,
                       const float* b1w, const float* b1b, const float* b1m, const float* b1v,
                       const float* b2w, const float* b2b, const float* b2m, const float* b2v,
                       const float* c8b, const float* t1, const float* t2, float* par) {
  const int c = threadIdx.x;
  const float s1 = b1w[c] * rsqrtf(b1v[c] + 1e-5f);
  par[c] = s1;
  par[256 + c] = b1b[c] - b1m[c] * s1;
  const float s2 = b2w[c] * rsqrtf(b2v[c] + 1e-5f);
  par[512 + c] = s2;
  par[768 + c] = b2b[c] - b2m[c] * s2;
  par[1024 + c] = c8b[c];
  par[1280 + c] = lnw[c];
  par[1536 + c] = lnb[c];
  par[1792 + c] = gam[c];
  if (c < 8) { par[2048 + c] = t1[c]; par[2056 + c] = t2[c]; }
}

// ------- conv weight repack+cast: w[co][ci][27] -> wp[tap][cb][co][32ci] -------
__global__ __launch_bounds__(256) void packw_k(const float* __restrict__ w,
                                               u16* __restrict__ wp) {
  __shared__ u16 lw[6912];          // [ci*27 + tap]
  const int co = blockIdx.x;
  const int tid = threadIdx.x;
  const float* src = w + (size_t)co * 6912;
  for (int i = tid; i < 6912; i += 256) lw[i] = f2b(src[i]);
  __syncthreads();
  const int ci = tid;
  for (int tap = 0; tap < 27; ++tap)
    wp[((size_t)(tap * 8 + (ci >> 5)) * 256 + co) * 32 + (ci & 31)] = lw[ci * 27 + tap];
}

// ------- remaining packs: EF^T; qw -> [cb][1024co][32]; w8 -> [cb][256co][32] --
__global__ void pack_rest_k(const float* __restrict__ EF, const float* __restrict__ qw,
                            const float* __restrict__ w8,
                            u16* __restrict__ eft, u16* __restrict__ qwb,
                            u16* __restrict__ w8b) {
  const int idx = blockIdx.x * 256 + threadIdx.x;
  if (idx < 262144) {
    const int pp = idx >> 12, n = idx & 4095;
    eft[idx] = f2b(EF[(size_t)n * 64 + pp]);
  } else if (idx < 524288) {
    const int j = idx - 262144;
    const int co = j >> 8, ci = j & 255;
    qwb[((size_t)(ci >> 5) * 1024 + co) * 32 + (ci & 31)] = f2b(qw[j]);
  } else if (idx < 589824) {
    const int j = idx - 524288;
    const int co = j >> 8, ci = j & 255;
    w8b[((size_t)(ci >> 5) * 256 + co) * 32 + (ci & 31)] = f2b(w8[j]);
  }
}

// ------- fused LayerNorm + transpose: x[b][c][n] -> token-major bf16 [b][n][c] -
__global__ __launch_bounds__(256) void ln_tm_k(const float* __restrict__ x,
                                               const float* __restrict__ par,
                                               u16* __restrict__ dst) {
  const int f = blockIdx.x;
  const int nt = (f & 7) * 8 + ((f >> 3) & 7);
  const int b = f >> 6;
  const int n0 = nt * 64;
  const int tid = threadIdx.x;
  __shared__ float tile[64 * 257];
  __shared__ float smu[64], srs[64];
  for (int j = 0; j < 64; ++j) {
    const int idx = j * 256 + tid;
    const int c = idx >> 6, nl = idx & 63;
    tile[nl * 257 + c] = x[(size_t)(b * 256 + c) * 4096 + n0 + nl];
  }
  __syncthreads();
  {
    const int tl = tid >> 2, p = tid & 3;
    float s = 0.f, q = 0.f;
#pragma unroll
    for (int k = 0; k < 64; ++k) {
      const float v = tile[tl * 257 + p * 64 + k];
      s += v; q += v * v;
    }
    s += __shfl_xor(s, 1, 64); q += __shfl_xor(q, 1, 64);
    s += __shfl_xor(s, 2, 64); q += __shfl_xor(q, 2, 64);
    if (p == 0) {
      const float mu = s * (1.0f / 256.0f);
      smu[tl] = mu;
      srs[tl] = rsqrtf(q * (1.0f / 256.0f) - mu * mu + 1e-5f);
    }
  }
  __syncthreads();
  const float lw = par[1280 + tid], lb = par[1536 + tid];
  for (int nl = 0; nl < 64; ++nl) {
    const float v = (tile[nl * 257 + tid] - smu[nl]) * srs[nl] * lw + lb;
    dst[((size_t)b * 4096 + n0 + nl) * 256 + tid] = f2b(v);
  }
}

// ------- zero halo rows of both padded buffers [b][5832][256] ------------------
__global__ __launch_bounds__(256) void zero_halo_k(u16* __restrict__ pa,
                                                   u16* __restrict__ pb) {
  u16* base = blockIdx.z ? pb : pa;
  const int b = blockIdx.y;
  const int row = blockIdx.x * 64 + (threadIdx.x >> 2);
  const int q = threadIdx.x & 3;
  if (row >= 5832) return;
  const int h = row / 324;
  const int rem = row - h * 324;
  const int w = rem / 18;
  const int d = rem - w * 18;
  if (h == 0 || h == 17 || w == 0 || w == 17 || d == 0 || d == 17) {
    uint4 zz; zz.x = 0; zz.y = 0; zz.z = 0; zz.w = 0;
    uint4* p = (uint4*)(base + ((size_t)b * 5832 + row) * 256 + q * 64);
#pragma unroll
    for (int k = 0; k < 8; ++k) p[k] = zz;
  }
}

// ---------------- unified MFMA GEMM over token-major B -------------------------
// TAPS==27: block 64co x 64n, 4 waves tap-split (7/7/7/6), RUNTIME tap loop
//   (do NOT unroll -- spills), A packed [tap][cb][co][32] (1KB frag loads),
//   LDS reduce 2 rounds; token-major store. Grid 1024, 3 blocks/CU.
// TAPS==1 WIDE:  block 128co x 128n, wave 64x64 (acc[4][4]), A packed [cb][M][32].
// TAPS==1 !WIDE: block 128co x 64n, wave 64x32 (acc[4][2]).
template <int TAPS, int COT, int MODE, bool WIDE, typename OutT>
__global__ __launch_bounds__(256, 3) void gemm_k(
    const u16* __restrict__ A, const u16* __restrict__ Bsrc, OutT* __restrict__ Out,
    const float* __restrict__ sc, const float* __restrict__ sh,
    const u16* __restrict__ skip) {
  constexpr int NSP = (TAPS == 27) ? 5832 : 4096;
  constexpr int NRS = (TAPS == 27) ? 336 : (WIDE ? 128 : 64);
  constexpr int NI = NRS / 16;
  constexpr int NF = (TAPS == 27) ? 4 : (WIDE ? 4 : 2);
  constexpr int CO_TILE = (TAPS == 27) ? 64 : 128;
  constexpr int M = COT * CO_TILE;
  constexpr int LG = (COT == 8) ? 3 : (COT == 4) ? 2 : 1;
  constexpr int LDS_U16 = (TAPS == 27) ? ((MODE == 2) ? 25344 : 21504) : (NRS * 64);
  __shared__ __align__(16) u16 lds[LDS_U16];

  const int f = blockIdx.x;
  const int x = f & 7;
  const int q = f >> 3;
  int b, co0, n0 = 0, tile_org = 0;
  if constexpr (TAPS == 27) {
    const int cot = q & 3;
    const int j = (q >> 2) & 7;
    b = q >> 5;
    co0 = cot * 64;
    const int nt = x * 8 + j;
    n0 = nt * 64;
    const int h0 = n0 >> 8, w0 = (n0 >> 4) & 15;
    tile_org = h0 * 324 + w0 * 18;
  } else if constexpr (WIDE) {
    const int cot = q & (COT - 1);
    const int r2 = q >> LG;
    const int j = r2 & 3;
    b = r2 >> 2;
    co0 = cot * CO_TILE;
    n0 = (x * 4 + j) * 128;
  } else {
    const int cot = q & (COT - 1);
    const int r2 = q >> LG;
    const int j = r2 & 7;
    b = r2 >> 3;
    co0 = cot * CO_TILE;
    n0 = (x * 8 + j) * 64;
  }

  const int tid = threadIdx.x;
  const int wid = tid >> 6, lane = tid & 63, l15 = lane & 15, l4 = lane >> 4;

  f32x4 z; z[0] = 0.f; z[1] = 0.f; z[2] = 0.f; z[3] = 0.f;
  f32x4 acc[4][NF];
#pragma unroll
  for (int i = 0; i < 4; ++i)
#pragma unroll
    for (int jj = 0; jj < NF; ++jj) acc[i][jj] = z;

  const u16* bbase = Bsrc + (size_t)b * NSP * 256;

  auto stage = [&](int cb, int bsel) {
    const int ci0 = cb * 32;
    u16* dst = lds + bsel * (NRS * 32);
    for (int i = wid; i < NI; i += 4) {
      const int sp = i * 16 + (lane >> 2);
      int row;
      if constexpr (TAPS == 27)
        row = tile_org + sp + ((sp >= 108) + (sp >= 216)) * 216;
      else
        row = n0 + sp;
      const int chunk = (lane & 3) ^ ((sp >> 1) & 3);
      const u16* gp = bbase + (size_t)row * 256 + ci0 + chunk * 8;
      gload_lds16(gp, dst + i * 512);
    }
  };

  stage(0, 0);
  __syncthreads();

  for (int cb = 0; cb < 8; ++cb) {
    if (cb < 7) stage(cb + 1, (cb + 1) & 1);
    const u16* buf = lds + (cb & 1) * (NRS * 32);
    if constexpr (TAPS == 27) {
      // wave tap-split: waves 0..2 -> 7 taps, wave 3 -> 6 taps (runtime loop!)
      const int t0 = wid * 7;
      const int t1 = (wid == 3) ? 27 : (t0 + 7);
      for (int tap = t0; tap < t1; ++tap) {
        const u16* at = A + ((size_t)(tap * 8 + cb) * 256 + co0 + l15) * 32 + l4 * 8;
        bf16x8 af[4];
#pragma unroll
        for (int fm = 0; fm < 4; ++fm) af[fm] = *(const bf16x8*)(at + fm * 512);
        const int kh = tap / 9, kw = (tap / 3) % 3, kd = tap - (tap / 3) * 3;
        const int rb = kh * 108 + kw * 18 + kd + l15;
        bf16x8 bf[4];
#pragma unroll
        for (int fn = 0; fn < 4; ++fn) {
          const int r = rb + fn * 18;
          bf[fn] = *(const bf16x8*)(&buf[r * 32 + ((l4 ^ ((r >> 1) & 3)) << 3)]);
        }
#pragma unroll
        for (int fm = 0; fm < 4; ++fm)
#pragma unroll
          for (int fn = 0; fn < 4; ++fn)
            acc[fm][fn] = mfma16(af[fm], bf[fn], acc[fm][fn]);
      }
    } else if constexpr (WIDE) {
      const int wr = wid >> 1, wc = wid & 1;
      const u16* a0 = A + ((size_t)cb * M + co0 + wr * 64 + l15) * 32 + l4 * 8;
      bf16x8 af[4];
#pragma unroll
      for (int fm = 0; fm < 4; ++fm) af[fm] = *(const bf16x8*)(a0 + fm * 512);
      bf16x8 bf[4];
#pragma unroll
      for (int fn = 0; fn < 4; ++fn) {
        const int r = wc * 64 + fn * 16 + l15;
        bf[fn] = *(const bf16x8*)(&buf[r * 32 + ((l4 ^ ((r >> 1) & 3)) << 3)]);
      }
#pragma unroll
      for (int fm = 0; fm < 4; ++fm)
#pragma unroll
        for (int fn = 0; fn < 4; ++fn)
          acc[fm][fn] = mfma16(af[fm], bf[fn], acc[fm][fn]);
    } else {
      const int wr = wid >> 1, wc = wid & 1;
      const u16* a0 = A + ((size_t)cb * M + co0 + wr * 64 + l15) * 32 + l4 * 8;
      bf16x8 af[4];
#pragma unroll
      for (int fm = 0; fm < 4; ++fm) af[fm] = *(const bf16x8*)(a0 + fm * 512);
      const int r0 = wc * 32 + l15;
      const int r1 = r0 + 16;
      const bf16x8 bf0 = *(const bf16x8*)(&buf[r0 * 32 + ((l4 ^ ((r0 >> 1) & 3)) << 3)]);
      const bf16x8 bf1 = *(const bf16x8*)(&buf[r1 * 32 + ((l4 ^ ((r1 >> 1) & 3)) << 3)]);
#pragma unroll
      for (int fm = 0; fm < 4; ++fm) {
        acc[fm][0] = mfma16(af[fm], bf0, acc[fm][0]);
        acc[fm][1] = mfma16(af[fm], bf1, acc[fm][1]);
      }
    }
    __syncthreads();
  }

  if constexpr (TAPS == 27) {
    // reduce 4 wave-partials via LDS (stride-66 rows), epilogue, token-major store
    float* red = (float*)&lds[0];        // 4 waves * 2112 f32 = 33792 B
    float* sk = red + 8448;              // MODE2: 64*66 f32 = 16896 B
    if constexpr (MODE == 2) {
      for (int i = tid; i < 4096; i += 256) {
        const int rr = i >> 6, cc = i & 63;
        sk[rr * 66 + cc] = b2f(skip[(size_t)(b * 256 + co0 + rr) * 4096 + n0 + cc]);
      }
    }
#pragma unroll
    for (int half = 0; half < 2; ++half) {
      __syncthreads();
#pragma unroll
      for (int fm2 = 0; fm2 < 2; ++fm2)
#pragma unroll
        for (int fn = 0; fn < 4; ++fn)
#pragma unroll
          for (int reg = 0; reg < 4; ++reg)
            red[wid * 2112 + (fm2 * 16 + l4 * 4 + reg) * 66 + fn * 16 + l15] =
                acc[half * 2 + fm2][fn][reg];
      __syncthreads();
      for (int i = tid; i < 2048; i += 256) {
        const int col = i >> 5, rowl = i & 31;
        float v = red[rowl * 66 + col] + red[2112 + rowl * 66 + col] +
                  red[4224 + rowl * 66 + col] + red[6336 + rowl * 66 + col];
        const int co = co0 + half * 32 + rowl;
        const int n = n0 + col;
        v = v * sc[co] + sh[co];
        if constexpr (MODE == 2) v += sk[(half * 32 + rowl) * 66 + col];
        v = (v >= 0.0f) ? v : 0.01f * v;
        size_t orow;
        if constexpr (MODE == 1) {
          const int h = n >> 8, w = (n >> 4) & 15, d = n & 15;
          orow = (size_t)b * 5832 + (h + 1) * 324 + (w + 1) * 18 + (d + 1);
        } else {
          orow = (size_t)b * 4096 + n;
        }
        Out[orow * 256 + co] = f2b(v);
      }
    }
  } else if constexpr (WIDE) {
    const int wr = wid >> 1, wc = wid & 1;
#pragma unroll
    for (int fm = 0; fm < 4; ++fm)
#pragma unroll
      for (int fn = 0; fn < 4; ++fn)
#pragma unroll
        for (int r = 0; r < 4; ++r) {
          const int row = co0 + wr * 64 + fm * 16 + l4 * 4 + r;
          const int col = n0 + wc * 64 + fn * 16 + l15;
          float v = acc[fm][fn][r];
          if constexpr (MODE == 3) {
            v = v + sh[row] + b2f(skip[(size_t)(b * 256 + row) * 4096 + col]);
          }
          if constexpr (std::is_same_v<OutT, float>)
            Out[(size_t)(b * M + row) * 4096 + col] = v;
          else
            Out[(size_t)(b * M + row) * 4096 + col] = f2b(v);
        }
  } else {
    const int wr = wid >> 1, wc = wid & 1;
#pragma unroll
    for (int fm = 0; fm < 4; ++fm)
#pragma unroll
      for (int fn = 0; fn < 2; ++fn)
#pragma unroll
        for (int r = 0; r < 4; ++r) {
          const int row = co0 + wr * 64 + fm * 16 + l4 * 4 + r;
          const int col = n0 + wc * 32 + fn * 16 + l15;
          float v = acc[fm][fn][r];
          if constexpr (MODE == 3) {
            v = v + sh[row] + b2f(skip[(size_t)(b * 256 + row) * 4096 + col]);
          }
          if constexpr (std::is_same_v<OutT, float>)
            Out[(size_t)(b * M + row) * 4096 + col] = v;
          else
            Out[(size_t)(b * M + row) * 4096 + col] = f2b(v);
        }
  }
}

// ---------------- q/k token-dim norms -> reciprocals ---------------------------
__global__ __launch_bounds__(256) void norm_k(const u16* __restrict__ qkvvT,
                                              float* __restrict__ rn) {
  const int bi = blockIdx.x;
  const int b = bi >> 9, m = bi & 511;
  const u16* row = qkvvT + (size_t)(b * 1024 + m) * 4096;
  const int tid = threadIdx.x;
  float p = 0.f;
#pragma unroll
  for (int i = 0; i < 16; ++i) { const float v = b2f(row[tid + i * 256]); p += v * v; }
#pragma unroll
  for (int off = 1; off < 64; off <<= 1) p += __shfl_xor(p, off, 64);
  __shared__ float w4[4];
  if ((tid & 63) == 0) w4[tid >> 6] = p;
  __syncthreads();
  if (tid == 0) {
    const float t = w4[0] + w4[1] + w4[2] + w4[3];
    rn[b * 512 + m] = 1.0f / fmaxf(sqrtf(t), 1e-12f);
  }
}

// ------- Linformer projections via MFMA: kp2[cd][p] = sum_n K[cd][n]*EFt[p][n] -
__global__ __launch_bounds__(256) void kvproj_k(const u16* __restrict__ qkvvT,
                                                const u16* __restrict__ eft,
                                                const float* __restrict__ rn,
                                                const float* __restrict__ par,
                                                float* __restrict__ kp2,
                                                float* __restrict__ vp) {
  const int bx = blockIdx.x;
  const int b = bx >> 3, which = (bx >> 2) & 1, cdt = bx & 3;
  const int tid = threadIdx.x;
  const int wid = tid >> 6, lane = tid & 63, l15 = lane & 15, l4 = lane >> 4;
  __shared__ float red[4 * 2048];
  const u16* kb = qkvvT + (size_t)(b * 1024 + (which ? 768 : 256) + cdt * 64) * 4096;

  f32x4 z; z[0] = 0.f; z[1] = 0.f; z[2] = 0.f; z[3] = 0.f;
  f32x4 acc[4][4];
#pragma unroll
  for (int i = 0; i < 4; ++i)
#pragma unroll
    for (int j = 0; j < 4; ++j) acc[i][j] = z;

  for (int nc = 0; nc < 32; ++nc) {
    const int n = wid * 1024 + nc * 32 + l4 * 8;
    bf16x8 af[4], bf[4];
#pragma unroll
    for (int fm = 0; fm < 4; ++fm)
      af[fm] = *(const bf16x8*)(kb + (size_t)(fm * 16 + l15) * 4096 + n);
#pragma unroll
    for (int fn = 0; fn < 4; ++fn)
      bf[fn] = *(const bf16x8*)(eft + (size_t)(fn * 16 + l15) * 4096 + n);
#pragma unroll
    for (int fm = 0; fm < 4; ++fm)
#pragma unroll
      for (int fn = 0; fn < 4; ++fn)
        acc[fm][fn] = mfma16(af[fm], bf[fn], acc[fm][fn]);
  }

#pragma unroll
  for (int half = 0; half < 2; ++half) {
    __syncthreads();
#pragma unroll
    for (int fm2 = 0; fm2 < 2; ++fm2)
#pragma unroll
      for (int fn = 0; fn < 4; ++fn)
#pragma unroll
        for (int r = 0; r < 4; ++r)
          red[wid * 2048 + (fm2 * 16 + l4 * 4 + r) * 64 + fn * 16 + l15] =
              acc[half * 2 + fm2][fn][r];
    __syncthreads();
    for (int i = tid; i < 2048; i += 256) {
      float v = red[i] + red[i + 2048] + red[i + 4096] + red[i + 6144];
      const int cdl = half * 32 + (i >> 6), pl = i & 63;
      const int cdg = cdt * 64 + cdl;
      if (which == 0) {
        v *= par[2056 + (cdg >> 5)] * rn[b * 512 + cdg];
        kp2[(size_t)(b * 256 + cdg) * 64 + pl] = v;
      } else {
        vp[(size_t)(b * 256 + cdg) * 64 + pl] = v;
      }
    }
  }
}

// ---------------- channel attention: S=softmax(qn.kn^T * t1) -> P --------------
__global__ __launch_bounds__(256) void ca_s_k(const u16* __restrict__ qkvvT,
                                              const float* __restrict__ rn,
                                              const float* __restrict__ par,
                                              float* __restrict__ P) {
  const int bx = blockIdx.x;
  const int b = bx >> 3, h = bx & 7;
  const int tid = threadIdx.x;
  const int wid = tid >> 6, lane = tid & 63, l15 = lane & 15, l4 = lane >> 4;
  __shared__ float Sp[4 * 1024];
  __shared__ float Sf[1024];

  const u16* qb = qkvvT + (size_t)(b * 1024 + h * 32) * 4096;
  const u16* kb = qkvvT + (size_t)(b * 1024 + 256 + h * 32) * 4096;

  f32x4 z; z[0] = 0.f; z[1] = 0.f; z[2] = 0.f; z[3] = 0.f;
  f32x4 s00 = z, s01 = z, s10 = z, s11 = z;
  for (int nc = 0; nc < 32; ++nc) {
    const int n = wid * 1024 + nc * 32 + l4 * 8;
    const bf16x8 q0 = *(const bf16x8*)(qb + (size_t)l15 * 4096 + n);
    const bf16x8 q1 = *(const bf16x8*)(qb + (size_t)(16 + l15) * 4096 + n);
    const bf16x8 k0 = *(const bf16x8*)(kb + (size_t)l15 * 4096 + n);
    const bf16x8 k1 = *(const bf16x8*)(kb + (size_t)(16 + l15) * 4096 + n);
    s00 = mfma16(q0, k0, s00); s01 = mfma16(q0, k1, s01);
    s10 = mfma16(q1, k0, s10); s11 = mfma16(q1, k1, s11);
  }
#pragma unroll
  for (int r = 0; r < 4; ++r) {
    const int d0 = l4 * 4 + r;
    Sp[wid * 1024 + d0 * 32 + l15] = s00[r];
    Sp[wid * 1024 + d0 * 32 + 16 + l15] = s01[r];
    Sp[wid * 1024 + (16 + d0) * 32 + l15] = s10[r];
    Sp[wid * 1024 + (16 + d0) * 32 + 16 + l15] = s11[r];
  }
  __syncthreads();
  const float t1 = par[2048 + h];
  for (int idx = tid; idx < 1024; idx += 256) {
    const int d = idx >> 5, e = idx & 31;
    float s = Sp[idx] + Sp[1024 + idx] + Sp[2048 + idx] + Sp[3072 + idx];
    Sf[idx] = s * rn[b * 512 + h * 32 + d] * rn[b * 512 + 256 + h * 32 + e] * t1;
  }
  __syncthreads();
  if (tid < 32) {
    const int d = tid;
    float m = -1e30f;
#pragma unroll
    for (int e = 0; e < 32; ++e) m = fmaxf(m, Sf[d * 32 + e]);
    float ex[32];
    float sum = 0.f;
#pragma unroll
    for (int e = 0; e < 32; ++e) { const float t = __expf(Sf[d * 32 + e] - m); ex[e] = t; sum += t; }
    const float inv = 1.0f / sum;
    float* Pg = P + (size_t)(b * 8 + h) * 1024 + d * 32;
#pragma unroll
    for (int e = 0; e < 32; ++e) Pg[e] = ex[e] * inv;
  }
}

// ---------------- x_CA = P @ V_ca ; writes ax[b][n][c] (initializes ax) --------
__global__ __launch_bounds__(256) void ca_apply_k(const u16* __restrict__ qkvvT,
                                                  const float* __restrict__ P,
                                                  float* __restrict__ ax) {
  const int bx = blockIdx.x;
  const int b = bx >> 7, h = (bx >> 4) & 7, nc = bx & 15;
  const int tid = threadIdx.x;
  const int n = nc * 256 + tid;
  __shared__ float Pl[1024];
  for (int idx = tid; idx < 1024; idx += 256) Pl[idx] = P[(size_t)(b * 8 + h) * 1024 + idx];
  __syncthreads();
  float a[32];
#pragma unroll
  for (int d = 0; d < 32; ++d) a[d] = 0.f;
  const u16* vb = qkvvT + (size_t)(b * 1024 + 512 + h * 32) * 4096 + n;
  for (int e = 0; e < 32; ++e) {
    const float vv = b2f(vb[(size_t)e * 4096]);
#pragma unroll
    for (int d = 0; d < 32; ++d) a[d] += Pl[d * 32 + e] * vv;
  }
  float* ob = ax + (size_t)(b * 4096 + n) * 256 + h * 32;
#pragma unroll
  for (int d = 0; d < 32; d += 4) {
    f32x4 t; t[0] = a[d]; t[1] = a[d + 1]; t[2] = a[d + 2]; t[3] = a[d + 3];
    *(f32x4*)(ob + d) = t;
  }
}

// ------- spatial attention, one token per thread (no cross-lane ops) -----------
__global__ __launch_bounds__(256, 2) void sa_k(const u16* __restrict__ qkvvT,
                                               const float* __restrict__ kp2,
                                               const float* __restrict__ vp,
                                               float* __restrict__ ax) {
  const int bx = blockIdx.x;
  const int b = bx >> 7, h = (bx >> 4) & 7, nc = bx & 15;
  const int n0 = nc * 256;
  const int tid = threadIdx.x;
  __shared__ float kpl[32 * 65], vpl[32 * 65];
  __shared__ u16 ql[32 * 260];
  for (int idx = tid; idx < 2048; idx += 256) {
    const int d = idx >> 6, pp = idx & 63;
    kpl[d * 65 + pp] = kp2[(size_t)(b * 256 + h * 32 + d) * 64 + pp];
    vpl[d * 65 + pp] = vp[(size_t)(b * 256 + h * 32 + d) * 64 + pp];
  }
  for (int d = 0; d < 32; ++d)
    ql[d * 260 + tid] = qkvvT[(size_t)(b * 1024 + h * 32 + d) * 4096 + n0 + tid];
  __syncthreads();

  float qv[32];
#pragma unroll
  for (int d = 0; d < 32; ++d) qv[d] = b2f(ql[d * 260 + tid]);

  float s[64];
  float m = -1e30f;
#pragma unroll
  for (int p = 0; p < 64; ++p) {
    float t = 0.f;
#pragma unroll
    for (int d = 0; d < 32; ++d) t += qv[d] * kpl[d * 65 + p];
    s[p] = t;
    m = fmaxf(m, t);
  }

  float out[32];
#pragma unroll
  for (int d = 0; d < 32; ++d) out[d] = 0.f;
  float sum = 0.f;
#pragma unroll
  for (int p = 0; p < 64; ++p) {
    const float e = __expf(s[p] - m);
    sum += e;
#pragma unroll
    for (int d = 0; d < 32; ++d) out[d] += e * vpl[d * 65 + p];
  }
  const float inv = 1.0f / sum;

  float* ob = ax + ((size_t)b * 4096 + (size_t)h * 16 + nc) * 256 + tid;
#pragma unroll
  for (int d = 0; d < 32; ++d)
    ob[(size_t)d * 32768] += out[d] * inv;
}

// ------- attn_skip: channel-major askip AND padded token-major xpad ------------
__global__ __launch_bounds__(256) void comb_k(const float* __restrict__ x,
                                              const float* __restrict__ ax,
                                              const float* __restrict__ par,
                                              u16* __restrict__ askip,
                                              u16* __restrict__ xpad) {
  const int f = blockIdx.x;
  const int nt = (f & 7) * 8 + ((f >> 3) & 7);
  const int b = f >> 6;
  const int n0 = nt * 64;
  const int tid = threadIdx.x;
  __shared__ float tile[64 * 65];
  for (int c0 = 0; c0 < 256; c0 += 64) {
    __syncthreads();
    for (int it = 0; it < 16; ++it) {
      const int idx = it * 256 + tid;
      const int nl = idx >> 6, cl = idx & 63;
      tile[nl * 65 + cl] = ax[(size_t)(b * 4096 + n0 + nl) * 256 + c0 + cl];
    }
    __syncthreads();
    for (int it = 0; it < 16; ++it) {
      const int idx = it * 256 + tid;
      const int cl = idx >> 6, nl = idx & 63;
      const int c = c0 + cl;
      const size_t o = (size_t)(b * 256 + c) * 4096 + n0 + nl;
      const float v = x[o] + par[1792 + c] * tile[nl * 65 + cl];
      askip[o] = f2b(v);
      tile[nl * 65 + cl] = v;
    }
    __syncthreads();
    for (int it = 0; it < 16; ++it) {
      const int idx = it * 256 + tid;
      const int nl = idx >> 6, cl = idx & 63;
      const int n = n0 + nl;
      const int h = n >> 8, w = (n >> 4) & 15, d = n & 15;
      const size_t orow = (size_t)b * 5832 + (h + 1) * 324 + (w + 1) * 18 + (d + 1);
      xpad[orow * 256 + c0 + cl] = f2b(tile[nl * 65 + cl]);
    }
  }
}

extern "C" void kernel_launch(void* const* d_in, const int* in_sizes, int n_in,
                              void* d_out, int out_size, void* d_ws, size_t ws_size,
                              hipStream_t stream) {
  (void)in_sizes; (void)n_in; (void)out_size; (void)ws_size;
  const float* x   = (const float*)d_in[0];
  const float* lnw = (const float*)d_in[1];
  const float* lnb = (const float*)d_in[2];
  const float* gam = (const float*)d_in[3];
  const float* qw  = (const float*)d_in[4];
  const float* EF  = (const float*)d_in[5];
  const float* t1  = (const float*)d_in[6];
  const float* t2  = (const float*)d_in[7];
  const float* c1w = (const float*)d_in[8];
  const float* c2w = (const float*)d_in[9];
  const float* b1w = (const float*)d_in[10];
  const float* b1b = (const float*)d_in[11];
  const float* b1m = (const float*)d_in[12];
  const float* b1v = (const float*)d_in[13];
  const float* b2w = (const float*)d_in[14];
  const float* b2b = (const float*)d_in[15];
  const float* b2m = (const float*)d_in[16];
  const float* b2v = (const float*)d_in[17];
  const float* c8w = (const float*)d_in[18];
  const float* c8b = (const float*)d_in[19];

  char* ws = (char*)d_ws;
  u16*   out2T = (u16*)(ws + 0ull);             // 8 MB
  u16*   qkvvT = (u16*)(ws + 8388608ull);       // 32 MB; after attention:
  u16*   xpadA = qkvvT;                         //   @8388608  11.94 MB
  u16*   xpadB = (u16*)(ws + 20709376ull);      //   11.94 MB (ends < 41943040)
  float* ax    = (float*)(ws + 41943040ull);    // 16 MB
  u16*   xn_tm = (u16*)(ws + 41943040ull);      // 8 MB (dead before ax written)
  u16*   askip = (u16*)(ws + 58720256ull);      // 8 MB
  u16*   wp1   = (u16*)(ws + 67108864ull);      // 3.54 MB
  u16*   wp2   = (u16*)(ws + 70647808ull);      // 3.54 MB
  u16*   eft   = (u16*)(ws + 74186752ull);      // 0.52 MB
  u16*   qwb   = (u16*)(ws + 74711040ull);      // 0.52 MB
  u16*   w8b   = (u16*)(ws + 75235328ull);      // 128 KB
  float* Pbuf  = (float*)(ws + 75366400ull);    // 128 KB
  float* kp2   = (float*)(ws + 75497472ull);    // 256 KB
  float* vp    = (float*)(ws + 75759616ull);    // 256 KB
  float* rn    = (float*)(ws + 76021760ull);    // 8 KB
  float* par   = (float*)(ws + 76029952ull);    // ~8 KB
  float* y = (float*)d_out;

  prep_k<<<dim3(1), dim3(256), 0, stream>>>(lnw, lnb, gam, b1w, b1b, b1m, b1v,
                                            b2w, b2b, b2m, b2v, c8b, t1, t2, par);
  packw_k<<<dim3(256), dim3(256), 0, stream>>>(c1w, wp1);
  packw_k<<<dim3(256), dim3(256), 0, stream>>>(c2w, wp2);
  pack_rest_k<<<dim3(2304), dim3(256), 0, stream>>>(EF, qw, c8w, eft, qwb, w8b);
  ln_tm_k<<<dim3(256), dim3(256), 0, stream>>>(x, par, xn_tm);
  gemm_k<1, 8, 0, true, u16><<<dim3(1024), dim3(256), 0, stream>>>(qwb, xn_tm, qkvvT,
                                                                   nullptr, nullptr, nullptr);
  norm_k<<<dim3(2048), dim3(256), 0, stream>>>(qkvvT, rn);
  kvproj_k<<<dim3(32), dim3(256), 0, stream>>>(qkvvT, eft, rn, par, kp2, vp);
  ca_s_k<<<dim3(32), dim3(256), 0, stream>>>(qkvvT, rn, par, Pbuf);
  ca_apply_k<<<dim3(512), dim3(256), 0, stream>>>(qkvvT, Pbuf, ax);
  sa_k<<<dim3(512), dim3(256), 0, stream>>>(qkvvT, kp2, vp, ax);
  zero_halo_k<<<dim3(92, 4, 2), dim3(256), 0, stream>>>(xpadA, xpadB);
  comb_k<<<dim3(256), dim3(256), 0, stream>>>(x, ax, par, askip, xpadA);
  gemm_k<27, 4, 1, false, u16><<<dim3(1024), dim3(256), 0, stream>>>(wp1, xpadA, xpadB,
                                                                     par + 0, par + 256, nullptr);
  gemm_k<27, 4, 2, false, u16><<<dim3(1024), dim3(256), 0, stream>>>(wp2, xpadB, out2T,
                                                                     par + 512, par + 768, askip);
  gemm_k<1, 2, 3, false, float><<<dim3(512), dim3(256), 0, stream>>>(w8b, out2T, y,
                                                                     nullptr, par + 1024, askip);
}

// Round 14
// 346.799 us; speedup vs baseline: 1.1248x; 1.1248x over previous
//
#include <hip/hip_runtime.h>
#include <stdint.h>
#include <type_traits>

typedef unsigned short u16;
typedef short bf16x8 __attribute__((ext_vector_type(8)));
typedef float f32x4 __attribute__((ext_vector_type(4)));

__device__ __forceinline__ float b2f(u16 u) {
  union { uint32_t i; float f; } z; z.i = ((uint32_t)u) << 16; return z.f;
}
__device__ __forceinline__ u16 f2b(float f) {
  union { float f; uint32_t i; } z; z.f = f;
  uint32_t u = z.i;
  return (u16)((u + 0x7fffu + ((u >> 16) & 1u)) >> 16);
}
__device__ __forceinline__ f32x4 mfma16(bf16x8 a, bf16x8 b, f32x4 c) {
  return __builtin_amdgcn_mfma_f32_16x16x32_bf16(a, b, c, 0, 0, 0);
}
__device__ __forceinline__ void gload_lds16(const void* gp, void* lp) {
  __builtin_amdgcn_global_load_lds((__attribute__((address_space(1))) void*)gp,
                                   (__attribute__((address_space(3))) void*)lp,
                                   16, 0, 0);
}

// ---------------- small param prep ----------------
// par layout (floats): 0 sc1 | 256 sh1 | 512 sc2 | 768 sh2 | 1024 b8 | 1280 lnw
//                      1536 lnb | 1792 gamma | 2048 t1[8] | 2056 t2[8]
__global__ void prep_k(const float* lnw, const float* lnb, const float* gam,
                       const float* b1w, const float* b1b, const float* b1m, const float* b1v,
                       const float* b2w, const float* b2b, const float* b2m, const float* b2v,
                       const float* c8b, const float* t1, const float* t2, float* par) {
  const int c = threadIdx.x;
  const float s1 = b1w[c] * rsqrtf(b1v[c] + 1e-5f);
  par[c] = s1;
  par[256 + c] = b1b[c] - b1m[c] * s1;
  const float s2 = b2w[c] * rsqrtf(b2v[c] + 1e-5f);
  par[512 + c] = s2;
  par[768 + c] = b2b[c] - b2m[c] * s2;
  par[1024 + c] = c8b[c];
  par[1280 + c] = lnw[c];
  par[1536 + c] = lnb[c];
  par[1792 + c] = gam[c];
  if (c < 8) { par[2048 + c] = t1[c]; par[2056 + c] = t2[c]; }
}

// ------- conv weight repack+cast: w[co][ci][27] -> wp[tap][cb][co][32ci] -------
__global__ __launch_bounds__(256) void packw_k(const float* __restrict__ w,
                                               u16* __restrict__ wp) {
  __shared__ u16 lw[6912];          // [ci*27 + tap]
  const int co = blockIdx.x;
  const int tid = threadIdx.x;
  const float* src = w + (size_t)co * 6912;
  for (int i = tid; i < 6912; i += 256) lw[i] = f2b(src[i]);
  __syncthreads();
  const int ci = tid;
  for (int tap = 0; tap < 27; ++tap)
    wp[((size_t)(tap * 8 + (ci >> 5)) * 256 + co) * 32 + (ci & 31)] = lw[ci * 27 + tap];
}

// ------- remaining packs: EF^T; qw -> [cb][1024co][32]; w8 -> [cb][256co][32] --
__global__ void pack_rest_k(const float* __restrict__ EF, const float* __restrict__ qw,
                            const float* __restrict__ w8,
                            u16* __restrict__ eft, u16* __restrict__ qwb,
                            u16* __restrict__ w8b) {
  const int idx = blockIdx.x * 256 + threadIdx.x;
  if (idx < 262144) {
    const int pp = idx >> 12, n = idx & 4095;
    eft[idx] = f2b(EF[(size_t)n * 64 + pp]);
  } else if (idx < 524288) {
    const int j = idx - 262144;
    const int co = j >> 8, ci = j & 255;
    qwb[((size_t)(ci >> 5) * 1024 + co) * 32 + (ci & 31)] = f2b(qw[j]);
  } else if (idx < 589824) {
    const int j = idx - 524288;
    const int co = j >> 8, ci = j & 255;
    w8b[((size_t)(ci >> 5) * 256 + co) * 32 + (ci & 31)] = f2b(w8[j]);
  }
}

// ------- fused LayerNorm + transpose: x[b][c][n] -> token-major bf16 [b][n][c] -
__global__ __launch_bounds__(256) void ln_tm_k(const float* __restrict__ x,
                                               const float* __restrict__ par,
                                               u16* __restrict__ dst) {
  const int f = blockIdx.x;
  const int nt = (f & 7) * 8 + ((f >> 3) & 7);
  const int b = f >> 6;
  const int n0 = nt * 64;
  const int tid = threadIdx.x;
  __shared__ float tile[64 * 257];
  __shared__ float smu[64], srs[64];
  for (int j = 0; j < 64; ++j) {
    const int idx = j * 256 + tid;
    const int c = idx >> 6, nl = idx & 63;
    tile[nl * 257 + c] = x[(size_t)(b * 256 + c) * 4096 + n0 + nl];
  }
  __syncthreads();
  {
    const int tl = tid >> 2, p = tid & 3;
    float s = 0.f, q = 0.f;
#pragma unroll
    for (int k = 0; k < 64; ++k) {
      const float v = tile[tl * 257 + p * 64 + k];
      s += v; q += v * v;
    }
    s += __shfl_xor(s, 1, 64); q += __shfl_xor(q, 1, 64);
    s += __shfl_xor(s, 2, 64); q += __shfl_xor(q, 2, 64);
    if (p == 0) {
      const float mu = s * (1.0f / 256.0f);
      smu[tl] = mu;
      srs[tl] = rsqrtf(q * (1.0f / 256.0f) - mu * mu + 1e-5f);
    }
  }
  __syncthreads();
  const float lw = par[1280 + tid], lb = par[1536 + tid];
  for (int nl = 0; nl < 64; ++nl) {
    const float v = (tile[nl * 257 + tid] - smu[nl]) * srs[nl] * lw + lb;
    dst[((size_t)b * 4096 + n0 + nl) * 256 + tid] = f2b(v);
  }
}

// ------- zero halo rows of both padded buffers [b][5832][256] ------------------
__global__ __launch_bounds__(256) void zero_halo_k(u16* __restrict__ pa,
                                                   u16* __restrict__ pb) {
  u16* base = blockIdx.z ? pb : pa;
  const int b = blockIdx.y;
  const int row = blockIdx.x * 64 + (threadIdx.x >> 2);
  const int q = threadIdx.x & 3;
  if (row >= 5832) return;
  const int h = row / 324;
  const int rem = row - h * 324;
  const int w = rem / 18;
  const int d = rem - w * 18;
  if (h == 0 || h == 17 || w == 0 || w == 17 || d == 0 || d == 17) {
    uint4 zz; zz.x = 0; zz.y = 0; zz.z = 0; zz.w = 0;
    uint4* p = (uint4*)(base + ((size_t)b * 5832 + row) * 256 + q * 64);
#pragma unroll
    for (int k = 0; k < 8; ++k) p[k] = zz;
  }
}

// ---------------- unified MFMA GEMM over token-major B -------------------------
// TAPS==27 (r12 config -- best measured): block 64co x 128n (2h x 4w x 16d),
//   4 waves tap-split (7/7/7/6), RUNTIME tap loop (do NOT unroll -- spills),
//   A packed [tap][cb][co][32] (1KB frag loads), LDS reduce 4 rounds;
//   token-major store. Grid 512 = 2 blocks/CU, launch_bounds(256,2).
// TAPS==1 WIDE:  block 128co x 128n, wave 64x64 (acc[4][4]), A packed [cb][M][32].
// TAPS==1 !WIDE: block 128co x 64n, wave 64x32 (acc[4][2]).
template <int TAPS, int COT, int MODE, bool WIDE, typename OutT>
__global__ __launch_bounds__(256, (TAPS == 27) ? 2 : 3) void gemm_k(
    const u16* __restrict__ A, const u16* __restrict__ Bsrc, OutT* __restrict__ Out,
    const float* __restrict__ sc, const float* __restrict__ sh,
    const u16* __restrict__ skip) {
  constexpr int NSP = (TAPS == 27) ? 5832 : 4096;
  constexpr int NRS = (TAPS == 27) ? 432 : (WIDE ? 128 : 64);
  constexpr int NI = NRS / 16;
  constexpr int NF = (TAPS == 27) ? 8 : (WIDE ? 4 : 2);
  constexpr int CO_TILE = (TAPS == 27) ? 64 : 128;
  constexpr int M = COT * CO_TILE;
  constexpr int LG = (COT == 8) ? 3 : (COT == 4) ? 2 : 1;
  constexpr int LDS_U16 = (TAPS == 27) ? 27648 : (NRS * 64);
  __shared__ __align__(16) u16 lds[LDS_U16];

  const int f = blockIdx.x;
  const int x = f & 7;
  const int q = f >> 3;
  int b, co0, n0 = 0, h0 = 0, w0 = 0, tile_org = 0;
  if constexpr (TAPS == 27) {
    const int cot = q & 3;
    const int j = (q >> 2) & 3;
    b = q >> 4;
    co0 = cot * 64;
    const int nt = x * 4 + j;          // h-pair = x, w-quad = j
    h0 = (nt >> 2) * 2;
    w0 = (nt & 3) * 4;
    tile_org = h0 * 324 + w0 * 18;
  } else if constexpr (WIDE) {
    const int cot = q & (COT - 1);
    const int r2 = q >> LG;
    const int j = r2 & 3;
    b = r2 >> 2;
    co0 = cot * CO_TILE;
    n0 = (x * 4 + j) * 128;
  } else {
    const int cot = q & (COT - 1);
    const int r2 = q >> LG;
    const int j = r2 & 7;
    b = r2 >> 3;
    co0 = cot * CO_TILE;
    n0 = (x * 8 + j) * 64;
  }

  const int tid = threadIdx.x;
  const int wid = tid >> 6, lane = tid & 63, l15 = lane & 15, l4 = lane >> 4;

  f32x4 z; z[0] = 0.f; z[1] = 0.f; z[2] = 0.f; z[3] = 0.f;
  f32x4 acc[4][NF];
#pragma unroll
  for (int i = 0; i < 4; ++i)
#pragma unroll
    for (int jj = 0; jj < NF; ++jj) acc[i][jj] = z;

  const u16* bbase = Bsrc + (size_t)b * NSP * 256;

  auto stage = [&](int cb, int bsel) {
    const int ci0 = cb * 32;
    u16* dst = lds + bsel * (NRS * 32);
    for (int i = wid; i < NI; i += 4) {
      const int sp = i * 16 + (lane >> 2);
      int row;
      if constexpr (TAPS == 27)
        row = tile_org + sp + ((sp >= 108) + (sp >= 216) + (sp >= 324)) * 216;
      else
        row = n0 + sp;
      const int chunk = (lane & 3) ^ ((sp >> 1) & 3);
      const u16* gp = bbase + (size_t)row * 256 + ci0 + chunk * 8;
      gload_lds16(gp, dst + i * 512);
    }
  };

  stage(0, 0);
  __syncthreads();

  for (int cb = 0; cb < 8; ++cb) {
    if (cb < 7) stage(cb + 1, (cb + 1) & 1);
    const u16* buf = lds + (cb & 1) * (NRS * 32);
    if constexpr (TAPS == 27) {
      // wave tap-split: waves 0..2 -> 7 taps, wave 3 -> 6 taps (runtime loop!)
      const int t0 = wid * 7;
      const int t1 = (wid == 3) ? 27 : (t0 + 7);
      for (int tap = t0; tap < t1; ++tap) {
        const u16* at = A + ((size_t)(tap * 8 + cb) * 256 + co0 + l15) * 32 + l4 * 8;
        bf16x8 af[4];
#pragma unroll
        for (int fm = 0; fm < 4; ++fm) af[fm] = *(const bf16x8*)(at + fm * 512);
        const int kh = tap / 9, kw = (tap / 3) % 3, kd = tap - (tap / 3) * 3;
        const int rb = kh * 108 + kw * 18 + kd + l15;
        bf16x8 bf[8];
#pragma unroll
        for (int fn = 0; fn < 8; ++fn) {
          const int r = rb + (fn >> 2) * 108 + (fn & 3) * 18;
          bf[fn] = *(const bf16x8*)(&buf[r * 32 + ((l4 ^ ((r >> 1) & 3)) << 3)]);
        }
#pragma unroll
        for (int fm = 0; fm < 4; ++fm)
#pragma unroll
          for (int fn = 0; fn < 8; ++fn)
            acc[fm][fn] = mfma16(af[fm], bf[fn], acc[fm][fn]);
      }
    } else if constexpr (WIDE) {
      const int wr = wid >> 1, wc = wid & 1;
      const u16* a0 = A + ((size_t)cb * M + co0 + wr * 64 + l15) * 32 + l4 * 8;
      bf16x8 af[4];
#pragma unroll
      for (int fm = 0; fm < 4; ++fm) af[fm] = *(const bf16x8*)(a0 + fm * 512);
      bf16x8 bf[4];
#pragma unroll
      for (int fn = 0; fn < 4; ++fn) {
        const int r = wc * 64 + fn * 16 + l15;
        bf[fn] = *(const bf16x8*)(&buf[r * 32 + ((l4 ^ ((r >> 1) & 3)) << 3)]);
      }
#pragma unroll
      for (int fm = 0; fm < 4; ++fm)
#pragma unroll
        for (int fn = 0; fn < 4; ++fn)
          acc[fm][fn] = mfma16(af[fm], bf[fn], acc[fm][fn]);
    } else {
      const int wr = wid >> 1, wc = wid & 1;
      const u16* a0 = A + ((size_t)cb * M + co0 + wr * 64 + l15) * 32 + l4 * 8;
      bf16x8 af[4];
#pragma unroll
      for (int fm = 0; fm < 4; ++fm) af[fm] = *(const bf16x8*)(a0 + fm * 512);
      const int r0 = wc * 32 + l15;
      const int r1 = r0 + 16;
      const bf16x8 bf0 = *(const bf16x8*)(&buf[r0 * 32 + ((l4 ^ ((r0 >> 1) & 3)) << 3)]);
      const bf16x8 bf1 = *(const bf16x8*)(&buf[r1 * 32 + ((l4 ^ ((r1 >> 1) & 3)) << 3)]);
#pragma unroll
      for (int fm = 0; fm < 4; ++fm) {
        acc[fm][0] = mfma16(af[fm], bf0, acc[fm][0]);
        acc[fm][1] = mfma16(af[fm], bf1, acc[fm][1]);
      }
    }
    __syncthreads();
  }

  if constexpr (TAPS == 27) {
    // reduce 4 wave-partials via LDS, 4 rounds of 16co x 128n; then epilogue.
    float* red = (float*)&lds[0];      // 4 waves * 2080 f32 = 33280 B (< 55296)
#pragma unroll
    for (int fm = 0; fm < 4; ++fm) {
      __syncthreads();
#pragma unroll
      for (int fn = 0; fn < 8; ++fn)
#pragma unroll
        for (int reg = 0; reg < 4; ++reg)
          red[wid * 2080 + (l4 * 4 + reg) * 130 + fn * 16 + l15] = acc[fm][fn][reg];
      __syncthreads();
      for (int i = tid; i < 2048; i += 256) {
        const int rowl = i >> 7, coll = i & 127;
        float v = red[rowl * 130 + coll] + red[2080 + rowl * 130 + coll] +
                  red[4160 + rowl * 130 + coll] + red[6240 + rowl * 130 + coll];
        const int co = co0 + fm * 16 + rowl;
        const int hl = coll >> 6, wl = (coll >> 4) & 3, d = coll & 15;
        v = v * sc[co] + sh[co];
        if constexpr (MODE == 2) {
          const int n = (h0 + hl) * 256 + (w0 + wl) * 16 + d;
          v += b2f(skip[(size_t)(b * 256 + co) * 4096 + n]);
        }
        v = (v >= 0.0f) ? v : 0.01f * v;
        size_t orow;
        if constexpr (MODE == 1)
          orow = (size_t)b * 5832 + (h0 + hl + 1) * 324 + (w0 + wl + 1) * 18 + d + 1;
        else
          orow = (size_t)b * 4096 + (h0 + hl) * 256 + (w0 + wl) * 16 + d;
        Out[orow * 256 + co] = f2b(v);
      }
    }
  } else if constexpr (WIDE) {
    const int wr = wid >> 1, wc = wid & 1;
#pragma unroll
    for (int fm = 0; fm < 4; ++fm)
#pragma unroll
      for (int fn = 0; fn < 4; ++fn)
#pragma unroll
        for (int r = 0; r < 4; ++r) {
          const int row = co0 + wr * 64 + fm * 16 + l4 * 4 + r;
          const int col = n0 + wc * 64 + fn * 16 + l15;
          float v = acc[fm][fn][r];
          if constexpr (MODE == 3) {
            v = v + sh[row] + b2f(skip[(size_t)(b * 256 + row) * 4096 + col]);
          }
          if constexpr (std::is_same_v<OutT, float>)
            Out[(size_t)(b * M + row) * 4096 + col] = v;
          else
            Out[(size_t)(b * M + row) * 4096 + col] = f2b(v);
        }
  } else {
    const int wr = wid >> 1, wc = wid & 1;
#pragma unroll
    for (int fm = 0; fm < 4; ++fm)
#pragma unroll
      for (int fn = 0; fn < 2; ++fn)
#pragma unroll
        for (int r = 0; r < 4; ++r) {
          const int row = co0 + wr * 64 + fm * 16 + l4 * 4 + r;
          const int col = n0 + wc * 32 + fn * 16 + l15;
          float v = acc[fm][fn][r];
          if constexpr (MODE == 3) {
            v = v + sh[row] + b2f(skip[(size_t)(b * 256 + row) * 4096 + col]);
          }
          if constexpr (std::is_same_v<OutT, float>)
            Out[(size_t)(b * M + row) * 4096 + col] = v;
          else
            Out[(size_t)(b * M + row) * 4096 + col] = f2b(v);
        }
  }
}

// ---------------- q/k token-dim norms -> reciprocals ---------------------------
__global__ __launch_bounds__(256) void norm_k(const u16* __restrict__ qkvvT,
                                              float* __restrict__ rn) {
  const int bi = blockIdx.x;
  const int b = bi >> 9, m = bi & 511;
  const u16* row = qkvvT + (size_t)(b * 1024 + m) * 4096;
  const int tid = threadIdx.x;
  float p = 0.f;
#pragma unroll
  for (int i = 0; i < 16; ++i) { const float v = b2f(row[tid + i * 256]); p += v * v; }
#pragma unroll
  for (int off = 1; off < 64; off <<= 1) p += __shfl_xor(p, off, 64);
  __shared__ float w4[4];
  if ((tid & 63) == 0) w4[tid >> 6] = p;
  __syncthreads();
  if (tid == 0) {
    const float t = w4[0] + w4[1] + w4[2] + w4[3];
    rn[b * 512 + m] = 1.0f / fmaxf(sqrtf(t), 1e-12f);
  }
}

// ------- Linformer projections via MFMA: kp2[cd][p] = sum_n K[cd][n]*EFt[p][n] -
__global__ __launch_bounds__(256) void kvproj_k(const u16* __restrict__ qkvvT,
                                                const u16* __restrict__ eft,
                                                const float* __restrict__ rn,
                                                const float* __restrict__ par,
                                                float* __restrict__ kp2,
                                                float* __restrict__ vp) {
  const int bx = blockIdx.x;
  const int b = bx >> 3, which = (bx >> 2) & 1, cdt = bx & 3;
  const int tid = threadIdx.x;
  const int wid = tid >> 6, lane = tid & 63, l15 = lane & 15, l4 = lane >> 4;
  __shared__ float red[4 * 2048];
  const u16* kb = qkvvT + (size_t)(b * 1024 + (which ? 768 : 256) + cdt * 64) * 4096;

  f32x4 z; z[0] = 0.f; z[1] = 0.f; z[2] = 0.f; z[3] = 0.f;
  f32x4 acc[4][4];
#pragma unroll
  for (int i = 0; i < 4; ++i)
#pragma unroll
    for (int j = 0; j < 4; ++j) acc[i][j] = z;

  for (int nc = 0; nc < 32; ++nc) {
    const int n = wid * 1024 + nc * 32 + l4 * 8;
    bf16x8 af[4], bf[4];
#pragma unroll
    for (int fm = 0; fm < 4; ++fm)
      af[fm] = *(const bf16x8*)(kb + (size_t)(fm * 16 + l15) * 4096 + n);
#pragma unroll
    for (int fn = 0; fn < 4; ++fn)
      bf[fn] = *(const bf16x8*)(eft + (size_t)(fn * 16 + l15) * 4096 + n);
#pragma unroll
    for (int fm = 0; fm < 4; ++fm)
#pragma unroll
      for (int fn = 0; fn < 4; ++fn)
        acc[fm][fn] = mfma16(af[fm], bf[fn], acc[fm][fn]);
  }

#pragma unroll
  for (int half = 0; half < 2; ++half) {
    __syncthreads();
#pragma unroll
    for (int fm2 = 0; fm2 < 2; ++fm2)
#pragma unroll
      for (int fn = 0; fn < 4; ++fn)
#pragma unroll
        for (int r = 0; r < 4; ++r)
          red[wid * 2048 + (fm2 * 16 + l4 * 4 + r) * 64 + fn * 16 + l15] =
              acc[half * 2 + fm2][fn][r];
    __syncthreads();
    for (int i = tid; i < 2048; i += 256) {
      float v = red[i] + red[i + 2048] + red[i + 4096] + red[i + 6144];
      const int cdl = half * 32 + (i >> 6), pl = i & 63;
      const int cdg = cdt * 64 + cdl;
      if (which == 0) {
        v *= par[2056 + (cdg >> 5)] * rn[b * 512 + cdg];
        kp2[(size_t)(b * 256 + cdg) * 64 + pl] = v;
      } else {
        vp[(size_t)(b * 256 + cdg) * 64 + pl] = v;
      }
    }
  }
}

// ---------------- channel attention: S=softmax(qn.kn^T * t1) -> P --------------
__global__ __launch_bounds__(256) void ca_s_k(const u16* __restrict__ qkvvT,
                                              const float* __restrict__ rn,
                                              const float* __restrict__ par,
                                              float* __restrict__ P) {
  const int bx = blockIdx.x;
  const int b = bx >> 3, h = bx & 7;
  const int tid = threadIdx.x;
  const int wid = tid >> 6, lane = tid & 63, l15 = lane & 15, l4 = lane >> 4;
  __shared__ float Sp[4 * 1024];
  __shared__ float Sf[1024];

  const u16* qb = qkvvT + (size_t)(b * 1024 + h * 32) * 4096;
  const u16* kb = qkvvT + (size_t)(b * 1024 + 256 + h * 32) * 4096;

  f32x4 z; z[0] = 0.f; z[1] = 0.f; z[2] = 0.f; z[3] = 0.f;
  f32x4 s00 = z, s01 = z, s10 = z, s11 = z;
  for (int nc = 0; nc < 32; ++nc) {
    const int n = wid * 1024 + nc * 32 + l4 * 8;
    const bf16x8 q0 = *(const bf16x8*)(qb + (size_t)l15 * 4096 + n);
    const bf16x8 q1 = *(const bf16x8*)(qb + (size_t)(16 + l15) * 4096 + n);
    const bf16x8 k0 = *(const bf16x8*)(kb + (size_t)l15 * 4096 + n);
    const bf16x8 k1 = *(const bf16x8*)(kb + (size_t)(16 + l15) * 4096 + n);
    s00 = mfma16(q0, k0, s00); s01 = mfma16(q0, k1, s01);
    s10 = mfma16(q1, k0, s10); s11 = mfma16(q1, k1, s11);
  }
#pragma unroll
  for (int r = 0; r < 4; ++r) {
    const int d0 = l4 * 4 + r;
    Sp[wid * 1024 + d0 * 32 + l15] = s00[r];
    Sp[wid * 1024 + d0 * 32 + 16 + l15] = s01[r];
    Sp[wid * 1024 + (16 + d0) * 32 + l15] = s10[r];
    Sp[wid * 1024 + (16 + d0) * 32 + 16 + l15] = s11[r];
  }
  __syncthreads();
  const float t1 = par[2048 + h];
  for (int idx = tid; idx < 1024; idx += 256) {
    const int d = idx >> 5, e = idx & 31;
    float s = Sp[idx] + Sp[1024 + idx] + Sp[2048 + idx] + Sp[3072 + idx];
    Sf[idx] = s * rn[b * 512 + h * 32 + d] * rn[b * 512 + 256 + h * 32 + e] * t1;
  }
  __syncthreads();
  if (tid < 32) {
    const int d = tid;
    float m = -1e30f;
#pragma unroll
    for (int e = 0; e < 32; ++e) m = fmaxf(m, Sf[d * 32 + e]);
    float ex[32];
    float sum = 0.f;
#pragma unroll
    for (int e = 0; e < 32; ++e) { const float t = __expf(Sf[d * 32 + e] - m); ex[e] = t; sum += t; }
    const float inv = 1.0f / sum;
    float* Pg = P + (size_t)(b * 8 + h) * 1024 + d * 32;
#pragma unroll
    for (int e = 0; e < 32; ++e) Pg[e] = ex[e] * inv;
  }
}

// ---------------- x_CA = P @ V_ca ; writes ax[b][n][c] (initializes ax) --------
__global__ __launch_bounds__(256) void ca_apply_k(const u16* __restrict__ qkvvT,
                                                  const float* __restrict__ P,
                                                  float* __restrict__ ax) {
  const int bx = blockIdx.x;
  const int b = bx >> 7, h = (bx >> 4) & 7, nc = bx & 15;
  const int tid = threadIdx.x;
  const int n = nc * 256 + tid;
  __shared__ float Pl[1024];
  for (int idx = tid; idx < 1024; idx += 256) Pl[idx] = P[(size_t)(b * 8 + h) * 1024 + idx];
  __syncthreads();
  float a[32];
#pragma unroll
  for (int d = 0; d < 32; ++d) a[d] = 0.f;
  const u16* vb = qkvvT + (size_t)(b * 1024 + 512 + h * 32) * 4096 + n;
  for (int e = 0; e < 32; ++e) {
    const float vv = b2f(vb[(size_t)e * 4096]);
#pragma unroll
    for (int d = 0; d < 32; ++d) a[d] += Pl[d * 32 + e] * vv;
  }
  float* ob = ax + (size_t)(b * 4096 + n) * 256 + h * 32;
#pragma unroll
  for (int d = 0; d < 32; d += 4) {
    f32x4 t; t[0] = a[d]; t[1] = a[d + 1]; t[2] = a[d + 2]; t[3] = a[d + 3];
    *(f32x4*)(ob + d) = t;
  }
}

// ------- spatial attention, one token per thread (no cross-lane ops) -----------
__global__ __launch_bounds__(256, 2) void sa_k(const u16* __restrict__ qkvvT,
                                               const float* __restrict__ kp2,
                                               const float* __restrict__ vp,
                                               float* __restrict__ ax) {
  const int bx = blockIdx.x;
  const int b = bx >> 7, h = (bx >> 4) & 7, nc = bx & 15;
  const int n0 = nc * 256;
  const int tid = threadIdx.x;
  __shared__ float kpl[32 * 65], vpl[32 * 65];
  __shared__ u16 ql[32 * 260];
  for (int idx = tid; idx < 2048; idx += 256) {
    const int d = idx >> 6, pp = idx & 63;
    kpl[d * 65 + pp] = kp2[(size_t)(b * 256 + h * 32 + d) * 64 + pp];
    vpl[d * 65 + pp] = vp[(size_t)(b * 256 + h * 32 + d) * 64 + pp];
  }
  for (int d = 0; d < 32; ++d)
    ql[d * 260 + tid] = qkvvT[(size_t)(b * 1024 + h * 32 + d) * 4096 + n0 + tid];
  __syncthreads();

  float qv[32];
#pragma unroll
  for (int d = 0; d < 32; ++d) qv[d] = b2f(ql[d * 260 + tid]);

  float s[64];
  float m = -1e30f;
#pragma unroll
  for (int p = 0; p < 64; ++p) {
    float t = 0.f;
#pragma unroll
    for (int d = 0; d < 32; ++d) t += qv[d] * kpl[d * 65 + p];
    s[p] = t;
    m = fmaxf(m, t);
  }

  float out[32];
#pragma unroll
  for (int d = 0; d < 32; ++d) out[d] = 0.f;
  float sum = 0.f;
#pragma unroll
  for (int p = 0; p < 64; ++p) {
    const float e = __expf(s[p] - m);
    sum += e;
#pragma unroll
    for (int d = 0; d < 32; ++d) out[d] += e * vpl[d * 65 + p];
  }
  const float inv = 1.0f / sum;

  float* ob = ax + ((size_t)b * 4096 + (size_t)h * 16 + nc) * 256 + tid;
#pragma unroll
  for (int d = 0; d < 32; ++d)
    ob[(size_t)d * 32768] += out[d] * inv;
}

// ------- attn_skip: channel-major askip AND padded token-major xpad ------------
__global__ __launch_bounds__(256) void comb_k(const float* __restrict__ x,
                                              const float* __restrict__ ax,
                                              const float* __restrict__ par,
                                              u16* __restrict__ askip,
                                              u16* __restrict__ xpad) {
  const int f = blockIdx.x;
  const int nt = (f & 7) * 8 + ((f >> 3) & 7);
  const int b = f >> 6;
  const int n0 = nt * 64;
  const int tid = threadIdx.x;
  __shared__ float tile[64 * 65];
  for (int c0 = 0; c0 < 256; c0 += 64) {
    __syncthreads();
    for (int it = 0; it < 16; ++it) {
      const int idx = it * 256 + tid;
      const int nl = idx >> 6, cl = idx & 63;
      tile[nl * 65 + cl] = ax[(size_t)(b * 4096 + n0 + nl) * 256 + c0 + cl];
    }
    __syncthreads();
    for (int it = 0; it < 16; ++it) {
      const int idx = it * 256 + tid;
      const int cl = idx >> 6, nl = idx & 63;
      const int c = c0 + cl;
      const size_t o = (size_t)(b * 256 + c) * 4096 + n0 + nl;
      const float v = x[o] + par[1792 + c] * tile[nl * 65 + cl];
      askip[o] = f2b(v);
      tile[nl * 65 + cl] = v;
    }
    __syncthreads();
    for (int it = 0; it < 16; ++it) {
      const int idx = it * 256 + tid;
      const int nl = idx >> 6, cl = idx & 63;
      const int n = n0 + nl;
      const int h = n >> 8, w = (n >> 4) & 15, d = n & 15;
      const size_t orow = (size_t)b * 5832 + (h + 1) * 324 + (w + 1) * 18 + (d + 1);
      xpad[orow * 256 + c0 + cl] = f2b(tile[nl * 65 + cl]);
    }
  }
}

extern "C" void kernel_launch(void* const* d_in, const int* in_sizes, int n_in,
                              void* d_out, int out_size, void* d_ws, size_t ws_size,
                              hipStream_t stream) {
  (void)in_sizes; (void)n_in; (void)out_size; (void)ws_size;
  const float* x   = (const float*)d_in[0];
  const float* lnw = (const float*)d_in[1];
  const float* lnb = (const float*)d_in[2];
  const float* gam = (const float*)d_in[3];
  const float* qw  = (const float*)d_in[4];
  const float* EF  = (const float*)d_in[5];
  const float* t1  = (const float*)d_in[6];
  const float* t2  = (const float*)d_in[7];
  const float* c1w = (const float*)d_in[8];
  const float* c2w = (const float*)d_in[9];
  const float* b1w = (const float*)d_in[10];
  const float* b1b = (const float*)d_in[11];
  const float* b1m = (const float*)d_in[12];
  const float* b1v = (const float*)d_in[13];
  const float* b2w = (const float*)d_in[14];
  const float* b2b = (const float*)d_in[15];
  const float* b2m = (const float*)d_in[16];
  const float* b2v = (const float*)d_in[17];
  const float* c8w = (const float*)d_in[18];
  const float* c8b = (const float*)d_in[19];

  char* ws = (char*)d_ws;
  u16*   out2T = (u16*)(ws + 0ull);             // 8 MB
  u16*   qkvvT = (u16*)(ws + 8388608ull);       // 32 MB; after attention:
  u16*   xpadA = qkvvT;                         //   @8388608  11.94 MB
  u16*   xpadB = (u16*)(ws + 20709376ull);      //   11.94 MB (ends < 41943040)
  float* ax    = (float*)(ws + 41943040ull);    // 16 MB
  u16*   xn_tm = (u16*)(ws + 41943040ull);      // 8 MB (dead before ax written)
  u16*   askip = (u16*)(ws + 58720256ull);      // 8 MB
  u16*   wp1   = (u16*)(ws + 67108864ull);      // 3.54 MB
  u16*   wp2   = (u16*)(ws + 70647808ull);      // 3.54 MB
  u16*   eft   = (u16*)(ws + 74186752ull);      // 0.52 MB
  u16*   qwb   = (u16*)(ws + 74711040ull);      // 0.52 MB
  u16*   w8b   = (u16*)(ws + 75235328ull);      // 128 KB
  float* Pbuf  = (float*)(ws + 75366400ull);    // 128 KB
  float* kp2   = (float*)(ws + 75497472ull);    // 256 KB
  float* vp    = (float*)(ws + 75759616ull);    // 256 KB
  float* rn    = (float*)(ws + 76021760ull);    // 8 KB
  float* par   = (float*)(ws + 76029952ull);    // ~8 KB
  float* y = (float*)d_out;

  prep_k<<<dim3(1), dim3(256), 0, stream>>>(lnw, lnb, gam, b1w, b1b, b1m, b1v,
                                            b2w, b2b, b2m, b2v, c8b, t1, t2, par);
  packw_k<<<dim3(256), dim3(256), 0, stream>>>(c1w, wp1);
  packw_k<<<dim3(256), dim3(256), 0, stream>>>(c2w, wp2);
  pack_rest_k<<<dim3(2304), dim3(256), 0, stream>>>(EF, qw, c8w, eft, qwb, w8b);
  ln_tm_k<<<dim3(256), dim3(256), 0, stream>>>(x, par, xn_tm);
  gemm_k<1, 8, 0, true, u16><<<dim3(1024), dim3(256), 0, stream>>>(qwb, xn_tm, qkvvT,
                                                                   nullptr, nullptr, nullptr);
  norm_k<<<dim3(2048), dim3(256), 0, stream>>>(qkvvT, rn);
  kvproj_k<<<dim3(32), dim3(256), 0, stream>>>(qkvvT, eft, rn, par, kp2, vp);
  ca_s_k<<<dim3(32), dim3(256), 0, stream>>>(qkvvT, rn, par, Pbuf);
  ca_apply_k<<<dim3(512), dim3(256), 0, stream>>>(qkvvT, Pbuf, ax);
  sa_k<<<dim3(512), dim3(256), 0, stream>>>(qkvvT, kp2, vp, ax);
  zero_halo_k<<<dim3(92, 4, 2), dim3(256), 0, stream>>>(xpadA, xpadB);
  comb_k<<<dim3(256), dim3(256), 0, stream>>>(x, ax, par, askip, xpadA);
  gemm_k<27, 4, 1, false, u16><<<dim3(512), dim3(256), 0, stream>>>(wp1, xpadA, xpadB,
                                                                    par + 0, par + 256, nullptr);
  gemm_k<27, 4, 2, false, u16><<<dim3(512), dim3(256), 0, stream>>>(wp2, xpadB, out2T,
                                                                    par + 512, par + 768, askip);
  gemm_k<1, 2, 3, true, float><<<dim3(256), dim3(256), 0, stream>>>(w8b, out2T, y,
                                                                    nullptr, par + 1024, askip);
}

// Round 15
// 320.178 us; speedup vs baseline: 1.2183x; 1.0831x over previous
//
#include <hip/hip_runtime.h>
#include <stdint.h>
#include <type_traits>

typedef unsigned short u16;
typedef short bf16x8 __attribute__((ext_vector_type(8)));
typedef float f32x4 __attribute__((ext_vector_type(4)));

__device__ __forceinline__ float b2f(u16 u) {
  union { uint32_t i; float f; } z; z.i = ((uint32_t)u) << 16; return z.f;
}
__device__ __forceinline__ u16 f2b(float f) {
  union { float f; uint32_t i; } z; z.f = f;
  uint32_t u = z.i;
  return (u16)((u + 0x7fffu + ((u >> 16) & 1u)) >> 16);
}
__device__ __forceinline__ f32x4 mfma16(bf16x8 a, bf16x8 b, f32x4 c) {
  return __builtin_amdgcn_mfma_f32_16x16x32_bf16(a, b, c, 0, 0, 0);
}
__device__ __forceinline__ void gload_lds16(const void* gp, void* lp) {
  __builtin_amdgcn_global_load_lds((__attribute__((address_space(1))) void*)gp,
                                   (__attribute__((address_space(3))) void*)lp,
                                   16, 0, 0);
}

// ---------------- small param prep ----------------
// par layout (floats): 0 sc1 | 256 sh1 | 512 sc2 | 768 sh2 | 1024 b8 | 1280 lnw
//                      1536 lnb | 1792 gamma | 2048 t1[8] | 2056 t2[8]
__global__ void prep_k(const float* lnw, const float* lnb, const float* gam,
                       const float* b1w, const float* b1b, const float* b1m, const float* b1v,
                       const float* b2w, const float* b2b, const float* b2m, const float* b2v,
                       const float* c8b, const float* t1, const float* t2, float* par) {
  const int c = threadIdx.x;
  const float s1 = b1w[c] * rsqrtf(b1v[c] + 1e-5f);
  par[c] = s1;
  par[256 + c] = b1b[c] - b1m[c] * s1;
  const float s2 = b2w[c] * rsqrtf(b2v[c] + 1e-5f);
  par[512 + c] = s2;
  par[768 + c] = b2b[c] - b2m[c] * s2;
  par[1024 + c] = c8b[c];
  par[1280 + c] = lnw[c];
  par[1536 + c] = lnb[c];
  par[1792 + c] = gam[c];
  if (c < 8) { par[2048 + c] = t1[c]; par[2056 + c] = t2[c]; }
}

// ------- conv weight repack+cast: w[co][ci][27] -> wp[tap][cb][co][32ci] -------
__global__ __launch_bounds__(256) void packw_k(const float* __restrict__ w,
                                               u16* __restrict__ wp) {
  __shared__ u16 lw[6912];          // [ci*27 + tap]
  const int co = blockIdx.x;
  const int tid = threadIdx.x;
  const float* src = w + (size_t)co * 6912;
  for (int i = tid; i < 6912; i += 256) lw[i] = f2b(src[i]);
  __syncthreads();
  const int ci = tid;
  for (int tap = 0; tap < 27; ++tap)
    wp[((size_t)(tap * 8 + (ci >> 5)) * 256 + co) * 32 + (ci & 31)] = lw[ci * 27 + tap];
}

// ------- EF transpose via LDS (coalesced both sides): EF[n][64] -> eft[p][4096]
__global__ __launch_bounds__(256) void eftpack_k(const float* __restrict__ EF,
                                                 u16* __restrict__ eft) {
  __shared__ u16 tile[64 * 65];
  const int n0 = blockIdx.x * 64;
  const int tid = threadIdx.x;
  for (int it = 0; it < 16; ++it) {
    const int idx = it * 256 + tid;
    const int r = idx >> 6, p = idx & 63;
    tile[p * 65 + r] = f2b(EF[(size_t)(n0 + r) * 64 + p]);
  }
  __syncthreads();
  for (int it = 0; it < 16; ++it) {
    const int idx = it * 256 + tid;
    const int p = idx >> 6, r = idx & 63;
    eft[(size_t)p * 4096 + n0 + r] = tile[p * 65 + r];
  }
}

// ------- remaining packs: qw -> [cb][1024co][32]; w8 -> [cb][256co][32] --------
__global__ void pack_rest_k(const float* __restrict__ qw, const float* __restrict__ w8,
                            u16* __restrict__ qwb, u16* __restrict__ w8b) {
  const int idx = blockIdx.x * 256 + threadIdx.x;
  if (idx < 262144) {
    const int co = idx >> 8, ci = idx & 255;
    qwb[((size_t)(ci >> 5) * 1024 + co) * 32 + (ci & 31)] = f2b(qw[idx]);
  } else if (idx < 327680) {
    const int j = idx - 262144;
    const int co = j >> 8, ci = j & 255;
    w8b[((size_t)(ci >> 5) * 256 + co) * 32 + (ci & 31)] = f2b(w8[j]);
  }
}

// ------- fused LayerNorm + transpose: x[b][c][n] -> token-major bf16 [b][n][c] -
__global__ __launch_bounds__(256) void ln_tm_k(const float* __restrict__ x,
                                               const float* __restrict__ par,
                                               u16* __restrict__ dst) {
  const int f = blockIdx.x;
  const int nt = (f & 7) * 8 + ((f >> 3) & 7);
  const int b = f >> 6;
  const int n0 = nt * 64;
  const int tid = threadIdx.x;
  __shared__ float tile[64 * 257];
  __shared__ float smu[64], srs[64];
  for (int j = 0; j < 64; ++j) {
    const int idx = j * 256 + tid;
    const int c = idx >> 6, nl = idx & 63;
    tile[nl * 257 + c] = x[(size_t)(b * 256 + c) * 4096 + n0 + nl];
  }
  __syncthreads();
  {
    const int tl = tid >> 2, p = tid & 3;
    float s = 0.f, q = 0.f;
#pragma unroll
    for (int k = 0; k < 64; ++k) {
      const float v = tile[tl * 257 + p * 64 + k];
      s += v; q += v * v;
    }
    s += __shfl_xor(s, 1, 64); q += __shfl_xor(q, 1, 64);
    s += __shfl_xor(s, 2, 64); q += __shfl_xor(q, 2, 64);
    if (p == 0) {
      const float mu = s * (1.0f / 256.0f);
      smu[tl] = mu;
      srs[tl] = rsqrtf(q * (1.0f / 256.0f) - mu * mu + 1e-5f);
    }
  }
  __syncthreads();
  const float lw = par[1280 + tid], lb = par[1536 + tid];
  for (int nl = 0; nl < 64; ++nl) {
    const float v = (tile[nl * 257 + tid] - smu[nl]) * srs[nl] * lw + lb;
    dst[((size_t)b * 4096 + n0 + nl) * 256 + tid] = f2b(v);
  }
}

// ------- zero halo rows of both padded buffers [b][5832][256] ------------------
__global__ __launch_bounds__(256) void zero_halo_k(u16* __restrict__ pa,
                                                   u16* __restrict__ pb) {
  u16* base = blockIdx.z ? pb : pa;
  const int b = blockIdx.y;
  const int row = blockIdx.x * 64 + (threadIdx.x >> 2);
  const int q = threadIdx.x & 3;
  if (row >= 5832) return;
  const int h = row / 324;
  const int rem = row - h * 324;
  const int w = rem / 18;
  const int d = rem - w * 18;
  if (h == 0 || h == 17 || w == 0 || w == 17 || d == 0 || d == 17) {
    uint4 zz; zz.x = 0; zz.y = 0; zz.z = 0; zz.w = 0;
    uint4* p = (uint4*)(base + ((size_t)b * 5832 + row) * 256 + q * 64);
#pragma unroll
    for (int k = 0; k < 8; ++k) p[k] = zz;
  }
}

// ---------------- unified MFMA GEMM over token-major B -------------------------
// TAPS==27 (r12 config -- best measured): block 64co x 128n (2h x 4w x 16d),
//   4 waves tap-split (7/7/7/6), RUNTIME tap loop (do NOT unroll -- spills),
//   A packed [tap][cb][co][32] (1KB frag loads), setprio(1) around MFMA cluster,
//   LDS reduce 4 rounds; token-major store. Grid 512 = 2 blocks/CU.
// TAPS==1 WIDE:  block 128co x 128n, wave 64x64 (acc[4][4]), A packed [cb][M][32].
// TAPS==1 !WIDE: block 128co x 64n, wave 64x32 (acc[4][2]).
template <int TAPS, int COT, int MODE, bool WIDE, typename OutT>
__global__ __launch_bounds__(256, (TAPS == 27) ? 2 : 3) void gemm_k(
    const u16* __restrict__ A, const u16* __restrict__ Bsrc, OutT* __restrict__ Out,
    const float* __restrict__ sc, const float* __restrict__ sh,
    const u16* __restrict__ skip) {
  constexpr int NSP = (TAPS == 27) ? 5832 : 4096;
  constexpr int NRS = (TAPS == 27) ? 432 : (WIDE ? 128 : 64);
  constexpr int NI = NRS / 16;
  constexpr int NF = (TAPS == 27) ? 8 : (WIDE ? 4 : 2);
  constexpr int CO_TILE = (TAPS == 27) ? 64 : 128;
  constexpr int M = COT * CO_TILE;
  constexpr int LG = (COT == 8) ? 3 : (COT == 4) ? 2 : 1;
  constexpr int LDS_U16 = (TAPS == 27) ? 27648 : (NRS * 64);
  __shared__ __align__(16) u16 lds[LDS_U16];

  const int f = blockIdx.x;
  const int x = f & 7;
  const int q = f >> 3;
  int b, co0, n0 = 0, h0 = 0, w0 = 0, tile_org = 0;
  if constexpr (TAPS == 27) {
    const int cot = q & 3;
    const int j = (q >> 2) & 3;
    b = q >> 4;
    co0 = cot * 64;
    const int nt = x * 4 + j;          // h-pair = x, w-quad = j
    h0 = (nt >> 2) * 2;
    w0 = (nt & 3) * 4;
    tile_org = h0 * 324 + w0 * 18;
  } else if constexpr (WIDE) {
    const int cot = q & (COT - 1);
    const int r2 = q >> LG;
    const int j = r2 & 3;
    b = r2 >> 2;
    co0 = cot * CO_TILE;
    n0 = (x * 4 + j) * 128;
  } else {
    const int cot = q & (COT - 1);
    const int r2 = q >> LG;
    const int j = r2 & 7;
    b = r2 >> 3;
    co0 = cot * CO_TILE;
    n0 = (x * 8 + j) * 64;
  }

  const int tid = threadIdx.x;
  const int wid = tid >> 6, lane = tid & 63, l15 = lane & 15, l4 = lane >> 4;

  f32x4 z; z[0] = 0.f; z[1] = 0.f; z[2] = 0.f; z[3] = 0.f;
  f32x4 acc[4][NF];
#pragma unroll
  for (int i = 0; i < 4; ++i)
#pragma unroll
    for (int jj = 0; jj < NF; ++jj) acc[i][jj] = z;

  const u16* bbase = Bsrc + (size_t)b * NSP * 256;

  auto stage = [&](int cb, int bsel) {
    const int ci0 = cb * 32;
    u16* dst = lds + bsel * (NRS * 32);
    for (int i = wid; i < NI; i += 4) {
      const int sp = i * 16 + (lane >> 2);
      int row;
      if constexpr (TAPS == 27)
        row = tile_org + sp + ((sp >= 108) + (sp >= 216) + (sp >= 324)) * 216;
      else
        row = n0 + sp;
      const int chunk = (lane & 3) ^ ((sp >> 1) & 3);
      const u16* gp = bbase + (size_t)row * 256 + ci0 + chunk * 8;
      gload_lds16(gp, dst + i * 512);
    }
  };

  stage(0, 0);
  __syncthreads();

  for (int cb = 0; cb < 8; ++cb) {
    if (cb < 7) stage(cb + 1, (cb + 1) & 1);
    const u16* buf = lds + (cb & 1) * (NRS * 32);
    if constexpr (TAPS == 27) {
      // wave tap-split: waves 0..2 -> 7 taps, wave 3 -> 6 taps (runtime loop!)
      const int t0 = wid * 7;
      const int t1 = (wid == 3) ? 27 : (t0 + 7);
      for (int tap = t0; tap < t1; ++tap) {
        const u16* at = A + ((size_t)(tap * 8 + cb) * 256 + co0 + l15) * 32 + l4 * 8;
        bf16x8 af[4];
#pragma unroll
        for (int fm = 0; fm < 4; ++fm) af[fm] = *(const bf16x8*)(at + fm * 512);
        const int kh = tap / 9, kw = (tap / 3) % 3, kd = tap - (tap / 3) * 3;
        const int rb = kh * 108 + kw * 18 + kd + l15;
        bf16x8 bf[8];
#pragma unroll
        for (int fn = 0; fn < 8; ++fn) {
          const int r = rb + (fn >> 2) * 108 + (fn & 3) * 18;
          bf[fn] = *(const bf16x8*)(&buf[r * 32 + ((l4 ^ ((r >> 1) & 3)) << 3)]);
        }
        __builtin_amdgcn_s_setprio(1);
#pragma unroll
        for (int fm = 0; fm < 4; ++fm)
#pragma unroll
          for (int fn = 0; fn < 8; ++fn)
            acc[fm][fn] = mfma16(af[fm], bf[fn], acc[fm][fn]);
        __builtin_amdgcn_s_setprio(0);
      }
    } else if constexpr (WIDE) {
      const int wr = wid >> 1, wc = wid & 1;
      const u16* a0 = A + ((size_t)cb * M + co0 + wr * 64 + l15) * 32 + l4 * 8;
      bf16x8 af[4];
#pragma unroll
      for (int fm = 0; fm < 4; ++fm) af[fm] = *(const bf16x8*)(a0 + fm * 512);
      bf16x8 bf[4];
#pragma unroll
      for (int fn = 0; fn < 4; ++fn) {
        const int r = wc * 64 + fn * 16 + l15;
        bf[fn] = *(const bf16x8*)(&buf[r * 32 + ((l4 ^ ((r >> 1) & 3)) << 3)]);
      }
#pragma unroll
      for (int fm = 0; fm < 4; ++fm)
#pragma unroll
        for (int fn = 0; fn < 4; ++fn)
          acc[fm][fn] = mfma16(af[fm], bf[fn], acc[fm][fn]);
    } else {
      const int wr = wid >> 1, wc = wid & 1;
      const u16* a0 = A + ((size_t)cb * M + co0 + wr * 64 + l15) * 32 + l4 * 8;
      bf16x8 af[4];
#pragma unroll
      for (int fm = 0; fm < 4; ++fm) af[fm] = *(const bf16x8*)(a0 + fm * 512);
      const int r0 = wc * 32 + l15;
      const int r1 = r0 + 16;
      const bf16x8 bf0 = *(const bf16x8*)(&buf[r0 * 32 + ((l4 ^ ((r0 >> 1) & 3)) << 3)]);
      const bf16x8 bf1 = *(const bf16x8*)(&buf[r1 * 32 + ((l4 ^ ((r1 >> 1) & 3)) << 3)]);
#pragma unroll
      for (int fm = 0; fm < 4; ++fm) {
        acc[fm][0] = mfma16(af[fm], bf0, acc[fm][0]);
        acc[fm][1] = mfma16(af[fm], bf1, acc[fm][1]);
      }
    }
    __syncthreads();
  }

  if constexpr (TAPS == 27) {
    // reduce 4 wave-partials via LDS, 4 rounds of 16co x 128n; then epilogue.
    float* red = (float*)&lds[0];      // 4 waves * 2080 f32 = 33280 B (< 55296)
#pragma unroll
    for (int fm = 0; fm < 4; ++fm) {
      __syncthreads();
#pragma unroll
      for (int fn = 0; fn < 8; ++fn)
#pragma unroll
        for (int reg = 0; reg < 4; ++reg)
          red[wid * 2080 + (l4 * 4 + reg) * 130 + fn * 16 + l15] = acc[fm][fn][reg];
      __syncthreads();
      for (int i = tid; i < 2048; i += 256) {
        const int rowl = i >> 7, coll = i & 127;
        float v = red[rowl * 130 + coll] + red[2080 + rowl * 130 + coll] +
                  red[4160 + rowl * 130 + coll] + red[6240 + rowl * 130 + coll];
        const int co = co0 + fm * 16 + rowl;
        const int hl = coll >> 6, wl = (coll >> 4) & 3, d = coll & 15;
        v = v * sc[co] + sh[co];
        if constexpr (MODE == 2) {
          const int n = (h0 + hl) * 256 + (w0 + wl) * 16 + d;
          v += b2f(skip[(size_t)(b * 256 + co) * 4096 + n]);
        }
        v = (v >= 0.0f) ? v : 0.01f * v;
        size_t orow;
        if constexpr (MODE == 1)
          orow = (size_t)b * 5832 + (h0 + hl + 1) * 324 + (w0 + wl + 1) * 18 + d + 1;
        else
          orow = (size_t)b * 4096 + (h0 + hl) * 256 + (w0 + wl) * 16 + d;
        Out[orow * 256 + co] = f2b(v);
      }
    }
  } else if constexpr (WIDE) {
    const int wr = wid >> 1, wc = wid & 1;
#pragma unroll
    for (int fm = 0; fm < 4; ++fm)
#pragma unroll
      for (int fn = 0; fn < 4; ++fn)
#pragma unroll
        for (int r = 0; r < 4; ++r) {
          const int row = co0 + wr * 64 + fm * 16 + l4 * 4 + r;
          const int col = n0 + wc * 64 + fn * 16 + l15;
          float v = acc[fm][fn][r];
          if constexpr (MODE == 3) {
            v = v + sh[row] + b2f(skip[(size_t)(b * 256 + row) * 4096 + col]);
          }
          if constexpr (std::is_same_v<OutT, float>)
            Out[(size_t)(b * M + row) * 4096 + col] = v;
          else
            Out[(size_t)(b * M + row) * 4096 + col] = f2b(v);
        }
  } else {
    const int wr = wid >> 1, wc = wid & 1;
#pragma unroll
    for (int fm = 0; fm < 4; ++fm)
#pragma unroll
      for (int fn = 0; fn < 2; ++fn)
#pragma unroll
        for (int r = 0; r < 4; ++r) {
          const int row = co0 + wr * 64 + fm * 16 + l4 * 4 + r;
          const int col = n0 + wc * 32 + fn * 16 + l15;
          float v = acc[fm][fn][r];
          if constexpr (MODE == 3) {
            v = v + sh[row] + b2f(skip[(size_t)(b * 256 + row) * 4096 + col]);
          }
          if constexpr (std::is_same_v<OutT, float>)
            Out[(size_t)(b * M + row) * 4096 + col] = v;
          else
            Out[(size_t)(b * M + row) * 4096 + col] = f2b(v);
        }
  }
}

// ---------------- q/k token-dim norms -> reciprocals ---------------------------
__global__ __launch_bounds__(256) void norm_k(const u16* __restrict__ qkvvT,
                                              float* __restrict__ rn) {
  const int bi = blockIdx.x;
  const int b = bi >> 9, m = bi & 511;
  const u16* row = qkvvT + (size_t)(b * 1024 + m) * 4096;
  const int tid = threadIdx.x;
  float p = 0.f;
#pragma unroll
  for (int i = 0; i < 16; ++i) { const float v = b2f(row[tid + i * 256]); p += v * v; }
#pragma unroll
  for (int off = 1; off < 64; off <<= 1) p += __shfl_xor(p, off, 64);
  __shared__ float w4[4];
  if ((tid & 63) == 0) w4[tid >> 6] = p;
  __syncthreads();
  if (tid == 0) {
    const float t = w4[0] + w4[1] + w4[2] + w4[3];
    rn[b * 512 + m] = 1.0f / fmaxf(sqrtf(t), 1e-12f);
  }
}

// ------- Linformer projections via MFMA, 128 blocks: (b, which, cdt16) ---------
// Each block: 16cd x 64p over K=4096; 4 waves split n; 1-round LDS reduce.
__global__ __launch_bounds__(256) void kvproj_k(const u16* __restrict__ qkvvT,
                                                const u16* __restrict__ eft,
                                                const float* __restrict__ rn,
                                                const float* __restrict__ par,
                                                float* __restrict__ kp2,
                                                float* __restrict__ vp) {
  const int bx = blockIdx.x;
  const int b = bx >> 5, which = (bx >> 4) & 1, cdt = bx & 15;
  const int tid = threadIdx.x;
  const int wid = tid >> 6, lane = tid & 63, l15 = lane & 15, l4 = lane >> 4;
  __shared__ float red[4 * 1024];
  const u16* kb = qkvvT + (size_t)(b * 1024 + (which ? 768 : 256) + cdt * 16) * 4096;

  f32x4 z; z[0] = 0.f; z[1] = 0.f; z[2] = 0.f; z[3] = 0.f;
  f32x4 acc[4] = {z, z, z, z};

  for (int nc = 0; nc < 32; ++nc) {
    const int n = wid * 1024 + nc * 32 + l4 * 8;
    const bf16x8 af = *(const bf16x8*)(kb + (size_t)l15 * 4096 + n);
    bf16x8 bf[4];
#pragma unroll
    for (int fn = 0; fn < 4; ++fn)
      bf[fn] = *(const bf16x8*)(eft + (size_t)(fn * 16 + l15) * 4096 + n);
#pragma unroll
    for (int fn = 0; fn < 4; ++fn)
      acc[fn] = mfma16(af, bf[fn], acc[fn]);
  }

  __syncthreads();
#pragma unroll
  for (int fn = 0; fn < 4; ++fn)
#pragma unroll
    for (int r = 0; r < 4; ++r)
      red[wid * 1024 + (l4 * 4 + r) * 64 + fn * 16 + l15] = acc[fn][r];
  __syncthreads();
  for (int i = tid; i < 1024; i += 256) {
    float v = red[i] + red[i + 1024] + red[i + 2048] + red[i + 3072];
    const int cdl = i >> 6, pl = i & 63;
    const int cdg = cdt * 16 + cdl;
    if (which == 0) {
      v *= par[2056 + (cdg >> 5)] * rn[b * 512 + cdg];
      kp2[(size_t)(b * 256 + cdg) * 64 + pl] = v;
    } else {
      vp[(size_t)(b * 256 + cdg) * 64 + pl] = v;
    }
  }
}

// ---------------- channel attention: S=softmax(qn.kn^T * t1) -> P --------------
__global__ __launch_bounds__(256) void ca_s_k(const u16* __restrict__ qkvvT,
                                              const float* __restrict__ rn,
                                              const float* __restrict__ par,
                                              float* __restrict__ P) {
  const int bx = blockIdx.x;
  const int b = bx >> 3, h = bx & 7;
  const int tid = threadIdx.x;
  const int wid = tid >> 6, lane = tid & 63, l15 = lane & 15, l4 = lane >> 4;
  __shared__ float Sp[4 * 1024];
  __shared__ float Sf[1024];

  const u16* qb = qkvvT + (size_t)(b * 1024 + h * 32) * 4096;
  const u16* kb = qkvvT + (size_t)(b * 1024 + 256 + h * 32) * 4096;

  f32x4 z; z[0] = 0.f; z[1] = 0.f; z[2] = 0.f; z[3] = 0.f;
  f32x4 s00 = z, s01 = z, s10 = z, s11 = z;
  for (int nc = 0; nc < 32; ++nc) {
    const int n = wid * 1024 + nc * 32 + l4 * 8;
    const bf16x8 q0 = *(const bf16x8*)(qb + (size_t)l15 * 4096 + n);
    const bf16x8 q1 = *(const bf16x8*)(qb + (size_t)(16 + l15) * 4096 + n);
    const bf16x8 k0 = *(const bf16x8*)(kb + (size_t)l15 * 4096 + n);
    const bf16x8 k1 = *(const bf16x8*)(kb + (size_t)(16 + l15) * 4096 + n);
    s00 = mfma16(q0, k0, s00); s01 = mfma16(q0, k1, s01);
    s10 = mfma16(q1, k0, s10); s11 = mfma16(q1, k1, s11);
  }
#pragma unroll
  for (int r = 0; r < 4; ++r) {
    const int d0 = l4 * 4 + r;
    Sp[wid * 1024 + d0 * 32 + l15] = s00[r];
    Sp[wid * 1024 + d0 * 32 + 16 + l15] = s01[r];
    Sp[wid * 1024 + (16 + d0) * 32 + l15] = s10[r];
    Sp[wid * 1024 + (16 + d0) * 32 + 16 + l15] = s11[r];
  }
  __syncthreads();
  const float t1 = par[2048 + h];
  for (int idx = tid; idx < 1024; idx += 256) {
    const int d = idx >> 5, e = idx & 31;
    float s = Sp[idx] + Sp[1024 + idx] + Sp[2048 + idx] + Sp[3072 + idx];
    Sf[idx] = s * rn[b * 512 + h * 32 + d] * rn[b * 512 + 256 + h * 32 + e] * t1;
  }
  __syncthreads();
  if (tid < 32) {
    const int d = tid;
    float m = -1e30f;
#pragma unroll
    for (int e = 0; e < 32; ++e) m = fmaxf(m, Sf[d * 32 + e]);
    float ex[32];
    float sum = 0.f;
#pragma unroll
    for (int e = 0; e < 32; ++e) { const float t = __expf(Sf[d * 32 + e] - m); ex[e] = t; sum += t; }
    const float inv = 1.0f / sum;
    float* Pg = P + (size_t)(b * 8 + h) * 1024 + d * 32;
#pragma unroll
    for (int e = 0; e < 32; ++e) Pg[e] = ex[e] * inv;
  }
}

// ---------------- x_CA = P @ V_ca ; writes ax[b][n][c] (initializes ax) --------
__global__ __launch_bounds__(256) void ca_apply_k(const u16* __restrict__ qkvvT,
                                                  const float* __restrict__ P,
                                                  float* __restrict__ ax) {
  const int bx = blockIdx.x;
  const int b = bx >> 7, h = (bx >> 4) & 7, nc = bx & 15;
  const int tid = threadIdx.x;
  const int n = nc * 256 + tid;
  __shared__ float Pl[1024];
  for (int idx = tid; idx < 1024; idx += 256) Pl[idx] = P[(size_t)(b * 8 + h) * 1024 + idx];
  __syncthreads();
  float a[32];
#pragma unroll
  for (int d = 0; d < 32; ++d) a[d] = 0.f;
  const u16* vb = qkvvT + (size_t)(b * 1024 + 512 + h * 32) * 4096 + n;
  for (int e = 0; e < 32; ++e) {
    const float vv = b2f(vb[(size_t)e * 4096]);
#pragma unroll
    for (int d = 0; d < 32; ++d) a[d] += Pl[d * 32 + e] * vv;
  }
  float* ob = ax + (size_t)(b * 4096 + n) * 256 + h * 32;
#pragma unroll
  for (int d = 0; d < 32; d += 4) {
    f32x4 t; t[0] = a[d]; t[1] = a[d + 1]; t[2] = a[d + 2]; t[3] = a[d + 3];
    *(f32x4*)(ob + d) = t;
  }
}

// ------- spatial attention, one token per thread (no cross-lane ops) -----------
__global__ __launch_bounds__(256, 2) void sa_k(const u16* __restrict__ qkvvT,
                                               const float* __restrict__ kp2,
                                               const float* __restrict__ vp,
                                               float* __restrict__ ax) {
  const int bx = blockIdx.x;
  const int b = bx >> 7, h = (bx >> 4) & 7, nc = bx & 15;
  const int n0 = nc * 256;
  const int tid = threadIdx.x;
  __shared__ float kpl[32 * 65], vpl[32 * 65];
  __shared__ u16 ql[32 * 260];
  for (int idx = tid; idx < 2048; idx += 256) {
    const int d = idx >> 6, pp = idx & 63;
    kpl[d * 65 + pp] = kp2[(size_t)(b * 256 + h * 32 + d) * 64 + pp];
    vpl[d * 65 + pp] = vp[(size_t)(b * 256 + h * 32 + d) * 64 + pp];
  }
  for (int d = 0; d < 32; ++d)
    ql[d * 260 + tid] = qkvvT[(size_t)(b * 1024 + h * 32 + d) * 4096 + n0 + tid];
  __syncthreads();

  float qv[32];
#pragma unroll
  for (int d = 0; d < 32; ++d) qv[d] = b2f(ql[d * 260 + tid]);

  float s[64];
  float m = -1e30f;
#pragma unroll
  for (int p = 0; p < 64; ++p) {
    float t = 0.f;
#pragma unroll
    for (int d = 0; d < 32; ++d) t += qv[d] * kpl[d * 65 + p];
    s[p] = t;
    m = fmaxf(m, t);
  }

  float out[32];
#pragma unroll
  for (int d = 0; d < 32; ++d) out[d] = 0.f;
  float sum = 0.f;
#pragma unroll
  for (int p = 0; p < 64; ++p) {
    const float e = __expf(s[p] - m);
    sum += e;
#pragma unroll
    for (int d = 0; d < 32; ++d) out[d] += e * vpl[d * 65 + p];
  }
  const float inv = 1.0f / sum;

  float* ob = ax + ((size_t)b * 4096 + (size_t)h * 16 + nc) * 256 + tid;
#pragma unroll
  for (int d = 0; d < 32; ++d)
    ob[(size_t)d * 32768] += out[d] * inv;
}

// ------- attn_skip: channel-major askip AND padded token-major xpad ------------
__global__ __launch_bounds__(256) void comb_k(const float* __restrict__ x,
                                              const float* __restrict__ ax,
                                              const float* __restrict__ par,
                                              u16* __restrict__ askip,
                                              u16* __restrict__ xpad) {
  const int f = blockIdx.x;
  const int nt = (f & 7) * 8 + ((f >> 3) & 7);
  const int b = f >> 6;
  const int n0 = nt * 64;
  const int tid = threadIdx.x;
  __shared__ float tile[64 * 65];
  for (int c0 = 0; c0 < 256; c0 += 64) {
    __syncthreads();
    for (int it = 0; it < 16; ++it) {
      const int idx = it * 256 + tid;
      const int nl = idx >> 6, cl = idx & 63;
      tile[nl * 65 + cl] = ax[(size_t)(b * 4096 + n0 + nl) * 256 + c0 + cl];
    }
    __syncthreads();
    for (int it = 0; it < 16; ++it) {
      const int idx = it * 256 + tid;
      const int cl = idx >> 6, nl = idx & 63;
      const int c = c0 + cl;
      const size_t o = (size_t)(b * 256 + c) * 4096 + n0 + nl;
      const float v = x[o] + par[1792 + c] * tile[nl * 65 + cl];
      askip[o] = f2b(v);
      tile[nl * 65 + cl] = v;
    }
    __syncthreads();
    for (int it = 0; it < 16; ++it) {
      const int idx = it * 256 + tid;
      const int nl = idx >> 6, cl = idx & 63;
      const int n = n0 + nl;
      const int h = n >> 8, w = (n >> 4) & 15, d = n & 15;
      const size_t orow = (size_t)b * 5832 + (h + 1) * 324 + (w + 1) * 18 + (d + 1);
      xpad[orow * 256 + c0 + cl] = f2b(tile[nl * 65 + cl]);
    }
  }
}

extern "C" void kernel_launch(void* const* d_in, const int* in_sizes, int n_in,
                              void* d_out, int out_size, void* d_ws, size_t ws_size,
                              hipStream_t stream) {
  (void)in_sizes; (void)n_in; (void)out_size; (void)ws_size;
  const float* x   = (const float*)d_in[0];
  const float* lnw = (const float*)d_in[1];
  const float* lnb = (const float*)d_in[2];
  const float* gam = (const float*)d_in[3];
  const float* qw  = (const float*)d_in[4];
  const float* EF  = (const float*)d_in[5];
  const float* t1  = (const float*)d_in[6];
  const float* t2  = (const float*)d_in[7];
  const float* c1w = (const float*)d_in[8];
  const float* c2w = (const float*)d_in[9];
  const float* b1w = (const float*)d_in[10];
  const float* b1b = (const float*)d_in[11];
  const float* b1m = (const float*)d_in[12];
  const float* b1v = (const float*)d_in[13];
  const float* b2w = (const float*)d_in[14];
  const float* b2b = (const float*)d_in[15];
  const float* b2m = (const float*)d_in[16];
  const float* b2v = (const float*)d_in[17];
  const float* c8w = (const float*)d_in[18];
  const float* c8b = (const float*)d_in[19];

  char* ws = (char*)d_ws;
  u16*   out2T = (u16*)(ws + 0ull);             // 8 MB
  u16*   qkvvT = (u16*)(ws + 8388608ull);       // 32 MB; after attention:
  u16*   xpadA = qkvvT;                         //   @8388608  11.94 MB
  u16*   xpadB = (u16*)(ws + 20709376ull);      //   11.94 MB (ends < 41943040)
  float* ax    = (float*)(ws + 41943040ull);    // 16 MB
  u16*   xn_tm = (u16*)(ws + 41943040ull);      // 8 MB (dead before ax written)
  u16*   askip = (u16*)(ws + 58720256ull);      // 8 MB
  u16*   wp1   = (u16*)(ws + 67108864ull);      // 3.54 MB
  u16*   wp2   = (u16*)(ws + 70647808ull);      // 3.54 MB
  u16*   eft   = (u16*)(ws + 74186752ull);      // 0.52 MB
  u16*   qwb   = (u16*)(ws + 74711040ull);      // 0.52 MB
  u16*   w8b   = (u16*)(ws + 75235328ull);      // 128 KB
  float* Pbuf  = (float*)(ws + 75366400ull);    // 128 KB
  float* kp2   = (float*)(ws + 75497472ull);    // 256 KB
  float* vp    = (float*)(ws + 75759616ull);    // 256 KB
  float* rn    = (float*)(ws + 76021760ull);    // 8 KB
  float* par   = (float*)(ws + 76029952ull);    // ~8 KB
  float* y = (float*)d_out;

  prep_k<<<dim3(1), dim3(256), 0, stream>>>(lnw, lnb, gam, b1w, b1b, b1m, b1v,
                                            b2w, b2b, b2m, b2v, c8b, t1, t2, par);
  packw_k<<<dim3(256), dim3(256), 0, stream>>>(c1w, wp1);
  packw_k<<<dim3(256), dim3(256), 0, stream>>>(c2w, wp2);
  eftpack_k<<<dim3(64), dim3(256), 0, stream>>>(EF, eft);
  pack_rest_k<<<dim3(1280), dim3(256), 0, stream>>>(qw, c8w, qwb, w8b);
  ln_tm_k<<<dim3(256), dim3(256), 0, stream>>>(x, par, xn_tm);
  gemm_k<1, 8, 0, true, u16><<<dim3(1024), dim3(256), 0, stream>>>(qwb, xn_tm, qkvvT,
                                                                   nullptr, nullptr, nullptr);
  norm_k<<<dim3(2048), dim3(256), 0, stream>>>(qkvvT, rn);
  kvproj_k<<<dim3(128), dim3(256), 0, stream>>>(qkvvT, eft, rn, par, kp2, vp);
  ca_s_k<<<dim3(32), dim3(256), 0, stream>>>(qkvvT, rn, par, Pbuf);
  ca_apply_k<<<dim3(512), dim3(256), 0, stream>>>(qkvvT, Pbuf, ax);
  sa_k<<<dim3(512), dim3(256), 0, stream>>>(qkvvT, kp2, vp, ax);
  zero_halo_k<<<dim3(92, 4, 2), dim3(256), 0, stream>>>(xpadA, xpadB);
  comb_k<<<dim3(256), dim3(256), 0, stream>>>(x, ax, par, askip, xpadA);
  gemm_k<27, 4, 1, false, u16><<<dim3(512), dim3(256), 0, stream>>>(wp1, xpadA, xpadB,
                                                                    par + 0, par + 256, nullptr);
  gemm_k<27, 4, 2, false, u16><<<dim3(512), dim3(256), 0, stream>>>(wp2, xpadB, out2T,
                                                                    par + 512, par + 768, askip);
  gemm_k<1, 2, 3, true, float><<<dim3(256), dim3(256), 0, stream>>>(w8b, out2T, y,
                                                                    nullptr, par + 1024, askip);
}